// Round 14
// baseline (195.952 us; speedup 1.0000x reference)
//
#include <hip/hip_runtime.h>
#include <hip/hip_bf16.h>

// Fused attention block: x@Wqkv -> RoPE -> causal GQA flash attention -> @Wo
// bf16 MFMA compute everywhere (2% abs tolerance), f32 I/O.

typedef __attribute__((ext_vector_type(8))) short short8;   // 8 bf16 = 4 VGPR (MFMA A/B frag)
typedef __attribute__((ext_vector_type(4))) float f32x4;    // 16x16 MFMA C/D frag
typedef __attribute__((ext_vector_type(16))) float f32x16;  // 32x32 MFMA C/D frag
typedef __attribute__((ext_vector_type(2))) int i32x2;
typedef __attribute__((ext_vector_type(4))) int i32x4;

__device__ __forceinline__ unsigned short f2bfu(float f){
  unsigned u = __float_as_uint(f);
  u += 0x7FFFu + ((u >> 16) & 1u);      // RNE (no NaNs in this workload)
  return (unsigned short)(u >> 16);
}
__device__ __forceinline__ float bfu2f(unsigned short u){
  return __uint_as_float(((unsigned)u) << 16);
}
// packed f32x2 -> bf16x2 (RNE), single VALU op
__device__ __forceinline__ unsigned cvt_pk_bf16(float lo, float hi){
  unsigned r;
  asm("v_cvt_pk_bf16_f32 %0, %1, %2" : "=v"(r) : "v"(lo), "v"(hi));
  return r;
}
// permlane32_swap: ret[0] = {a_lo, b_lo-of-partner}, ret[1] = {a_hi-of-partner, b_hi}
__device__ __forceinline__ i32x2 pl32swap(int a, int b){
  auto r = __builtin_amdgcn_permlane32_swap(a, b, false, false);
  return __builtin_bit_cast(i32x2, r);
}
// swizzled element offset in a 64-col bf16 row: slot = 16B unit 0..7, XOR row&7
__device__ __forceinline__ int swz64(int row, int slot){
  return row * 64 + (((slot) ^ (row & 7)) << 3);
}
template<int N> __device__ __forceinline__ void vm_wait(){
  if constexpr (N == 8)      asm volatile("s_waitcnt vmcnt(8)" ::: "memory");
  else if constexpr (N == 7) asm volatile("s_waitcnt vmcnt(7)" ::: "memory");
  else if constexpr (N == 6) asm volatile("s_waitcnt vmcnt(6)" ::: "memory");
  else if constexpr (N == 4) asm volatile("s_waitcnt vmcnt(4)" ::: "memory");
  else if constexpr (N == 3) asm volatile("s_waitcnt vmcnt(3)" ::: "memory");
  else if constexpr (N == 2) asm volatile("s_waitcnt vmcnt(2)" ::: "memory");
  else                       asm volatile("s_waitcnt vmcnt(0)" ::: "memory");
}

// ---------------- elementwise f32 -> bf16 ----------------
__global__ void convx_kernel(const float* __restrict__ x, unsigned short* __restrict__ xb, int n4){
  int i = blockIdx.x * blockDim.x + threadIdx.x;
  if (i >= n4) return;
  float4 v = reinterpret_cast<const float4*>(x)[i];
  ushort4 o;
  o.x = f2bfu(v.x); o.y = f2bfu(v.y); o.z = f2bfu(v.z); o.w = f2bfu(v.w);
  reinterpret_cast<ushort4*>(xb)[i] = o;
}

// ---------------- tiled transpose + convert: out[n][k] = (bf16)in[k][n] ----------------
__global__ void transpose_conv_kernel(const float* __restrict__ in, unsigned short* __restrict__ out,
                                      int Min, int Nin){
  __shared__ float t[32][33];
  int c0 = blockIdx.x * 32, r0 = blockIdx.y * 32;
  int tx = threadIdx.x, ty = threadIdx.y;   // 32 x 8
  #pragma unroll
  for (int i = ty; i < 32; i += 8) t[i][tx] = in[(size_t)(r0 + i) * Nin + c0 + tx];
  __syncthreads();
  #pragma unroll
  for (int i = ty; i < 32; i += 8) out[(size_t)(c0 + i) * Min + r0 + tx] = f2bfu(t[tx][i]);
}

// ========= 256 x (NF*64) 4-phase bf16 GEMM with pipelined fragment reads =========
// R11's verified 4-phase staging schedule + one change: fragment ds_reads for phase p+1
// issue DURING phase p into an alternate register set (double-buffered frags) -> the CU-wide
// LDS read burst overlaps the MFMA burst instead of serializing (m196's interleave lever).
// Wait re-derivation (read flight now 2 phases): publication point moves 1 phase earlier ->
// per-phase vmcnt(3) = "all but current phase's (<=4) stages complete" (prologue likewise);
// lgkmcnt(0) BEFORE each barrier makes cross-wave WAR on pre-read regions provable (reads
// done before any wave passes the barrier preceding that region's re-staging);
// sched_barrier(0) pins reads+staging above the MFMA cluster. Peeled tail: vmcnt 3 -> 0.
#define PH4P(NS,NK,CUR,NXT,VMW,...) { \
  const unsigned short* sAn = &sA[NS][(NK)*8192]; \
  const unsigned short* sBn = &sB[NS][(NK)*RB]; \
  _Pragma("unroll") for (int m_ = 0; m_ < 8; m_++) \
    afr[NXT][m_] = *reinterpret_cast<const short8*>(sAn + aOff[m_]); \
  _Pragma("unroll") for (int n_ = 0; n_ < NF; n_++) \
    bfr[NXT][n_] = *reinterpret_cast<const short8*>(sBn + bOff[n_]); \
  __VA_ARGS__; \
  __builtin_amdgcn_sched_barrier(0); \
  __builtin_amdgcn_s_setprio(1); \
  _Pragma("unroll") for (int m_ = 0; m_ < 8; m_++){ \
    _Pragma("unroll") for (int n_ = 0; n_ < NF; n_++){ \
      acc[m_][n_] = __builtin_amdgcn_mfma_f32_16x16x32_bf16(afr[CUR][m_], bfr[CUR][n_], acc[m_][n_], 0, 0, 0); }} \
  __builtin_amdgcn_s_setprio(0); \
  asm volatile("s_waitcnt lgkmcnt(0)" ::: "memory"); \
  VMW; \
  __builtin_amdgcn_s_barrier(); \
}
#define PH4L(CUR) { \
  __builtin_amdgcn_s_setprio(1); \
  _Pragma("unroll") for (int m_ = 0; m_ < 8; m_++){ \
    _Pragma("unroll") for (int n_ = 0; n_ < NF; n_++){ \
      acc[m_][n_] = __builtin_amdgcn_mfma_f32_16x16x32_bf16(afr[CUR][m_], bfr[CUR][n_], acc[m_][n_], 0, 0, 0); }} \
  __builtin_amdgcn_s_setprio(0); \
}

template<int NF, bool OUTBF16>
__global__ __launch_bounds__(512, 2) void gemm4p_kernel(const unsigned short* __restrict__ A,
                                                        const unsigned short* __restrict__ B,
                                                        void* __restrict__ Cp,
                                                        int M, int N, int K, int nbx){
  constexpr int RB   = NF * 2048;             // elems per B (slot,kk) region
  constexpr int VMS2 = (NF == 4) ? 4 : 3;     // leave only current phase's stages in flight
  __shared__ unsigned short sA[2][16384];     // 64 KiB
  __shared__ unsigned short sB[2][2 * RB];    // NF*32 KiB
  const int tid = threadIdx.x;
  const int l = tid & 63, w = tid >> 6;
  const int quad = l >> 4, c16 = l & 15;
  const int cpx = (int)gridDim.x >> 3;
  const int id2 = ((int)blockIdx.x & 7) * cpx + ((int)blockIdx.x >> 3);
  const int bx = id2 % nbx, by = id2 / nbx;
  const int row0 = by * 256, col0 = bx * (NF * 64);
  const int wr = w >> 2, wc = w & 3;

  const int rlA0 = w * 32 + (l >> 2), rlA1 = rlA0 + 16;
  const unsigned short* gA0 = A + (size_t)(row0 + rlA0) * K + (((l & 3) ^ ((rlA0 >> 1) & 3)) << 3);
  const unsigned short* gA1 = A + (size_t)(row0 + rlA1) * K + (((l & 3) ^ ((rlA1 >> 1) & 3)) << 3);
  const unsigned short* gB0;
  const unsigned short* gB1 = nullptr;
  const unsigned short* gB2 = nullptr;
  if constexpr (NF == 4){
    gB0 = B + (size_t)(col0 + rlA0) * K + (((l & 3) ^ ((rlA0 >> 1) & 3)) << 3);
    gB1 = B + (size_t)(col0 + rlA1) * K + (((l & 3) ^ ((rlA1 >> 1) & 3)) << 3);
  } else {
    const int rlB0 = w * 16 + (l >> 2);
    gB0 = B + (size_t)(col0 + rlB0) * K + (((l & 3) ^ ((rlB0 >> 1) & 3)) << 3);
    if constexpr (NF == 3){
      const int rlB2 = 128 + (w & 3) * 16 + (l >> 2);
      gB2 = B + (size_t)(col0 + rlB2) * K + (((l & 3) ^ ((rlB2 >> 1) & 3)) << 3);
    }
  }

  auto stA = [&](int slot, int kk, int col){
    __builtin_amdgcn_global_load_lds((const __attribute__((address_space(1))) void*)(gA0 + col),
        (__attribute__((address_space(3))) void*)(&sA[slot][kk * 8192 + w * 1024]), 16, 0, 0);
    __builtin_amdgcn_global_load_lds((const __attribute__((address_space(1))) void*)(gA1 + col),
        (__attribute__((address_space(3))) void*)(&sA[slot][kk * 8192 + w * 1024 + 512]), 16, 0, 0);
  };
  auto stB = [&](int slot, int kk, int col){
    if constexpr (NF == 4){
      __builtin_amdgcn_global_load_lds((const __attribute__((address_space(1))) void*)(gB0 + col),
          (__attribute__((address_space(3))) void*)(&sB[slot][kk * RB + w * 1024]), 16, 0, 0);
      __builtin_amdgcn_global_load_lds((const __attribute__((address_space(1))) void*)(gB1 + col),
          (__attribute__((address_space(3))) void*)(&sB[slot][kk * RB + w * 1024 + 512]), 16, 0, 0);
    } else if constexpr (NF == 3){
      __builtin_amdgcn_global_load_lds((const __attribute__((address_space(1))) void*)(gB0 + col),
          (__attribute__((address_space(3))) void*)(&sB[slot][kk * RB + w * 512]), 16, 0, 0);
      if ((kk == 0) ? (w < 4) : (w >= 4))    // wave-uniform; per-phase per-wave stages <= 4
        __builtin_amdgcn_global_load_lds((const __attribute__((address_space(1))) void*)(gB2 + col),
            (__attribute__((address_space(3))) void*)(&sB[slot][kk * RB + 4096 + (w & 3) * 512]), 16, 0, 0);
    } else {
      __builtin_amdgcn_global_load_lds((const __attribute__((address_space(1))) void*)(gB0 + col),
          (__attribute__((address_space(3))) void*)(&sB[slot][kk * RB + w * 512]), 16, 0, 0);
    }
  };

  int aOff[8], bOff[4];
  #pragma unroll
  for (int mf = 0; mf < 8; mf++){
    int row = wr * 128 + mf * 16 + c16;
    aOff[mf] = row * 32 + ((quad ^ ((row >> 1) & 3)) << 3);
  }
  #pragma unroll
  for (int nf = 0; nf < 4; nf++){
    int row = wc * (NF * 16) + nf * 16 + c16;
    bOff[nf] = row * 32 + ((quad ^ ((row >> 1) & 3)) << 3);
  }

  // prologue: stage (0,0),(0,1),(1,0); vmcnt(VMS2) -> (0,0) AND (0,1) complete (first
  // loop phase pre-reads (0,1)); then read set-0 frags from (0,0).
  stA(0, 0, 0);  stB(0, 0, 0);
  stA(0, 1, 32); stB(0, 1, 32);
  stA(1, 0, 64); stB(1, 0, 64);
  vm_wait<VMS2>();
  __builtin_amdgcn_s_barrier();

  f32x4 acc[8][4] = {};
  short8 afr[2][8];
  short8 bfr[2][4];
  #pragma unroll
  for (int m_ = 0; m_ < 8; m_++) afr[0][m_] = *reinterpret_cast<const short8*>(&sA[0][0] + aOff[m_]);
  #pragma unroll
  for (int n_ = 0; n_ < NF; n_++) bfr[0][n_] = *reinterpret_cast<const short8*>(&sB[0][0] + bOff[n_]);

  const int NI = K >> 7;   // iterations of 2 K-tiles (BK=64)
  #pragma unroll 1
  for (int j = 0; j < NI - 1; ++j){
    const int t1c  = (2 * j + 1) * 64 + 32;  // tile 2j+1, k1
    const int t2c0 = (2 * j + 2) * 64;       // tile 2j+2, k0
    const int t2c1 = t2c0 + 32;
    const int t3c0 = (2 * j + 3) * 64;       // tile 2j+3, k0
    PH4P(0,1, 0,1, vm_wait<VMS2>(), stA(1,1,t1c);  stB(1,1,t1c))   // cur (0,0), next (0,1)
    PH4P(1,0, 1,0, vm_wait<VMS2>(), stA(0,0,t2c0); stB(0,0,t2c0))  // cur (0,1), next (1,0)
    PH4P(1,1, 0,1, vm_wait<VMS2>(), stA(0,1,t2c1); stB(0,1,t2c1))  // cur (1,0), next (1,1)
    PH4P(0,0, 1,0, vm_wait<VMS2>(), stA(1,0,t3c0); stB(1,0,t3c0))  // cur (1,1), next (0,0)
  }
  { // peeled last iteration: only the last tile's k1 remains to stage
    const int t1c = K - 32;
    PH4P(0,1, 0,1, vm_wait<VMS2>(), stA(1,1,t1c); stB(1,1,t1c))
    PH4P(1,0, 1,0, vm_wait<0>(), ;)
    PH4P(1,1, 0,1, (void)0, ;)
    PH4L(1)
  }

  // epilogue
  #pragma unroll
  for (int mf = 0; mf < 8; mf++)
    #pragma unroll
    for (int nf = 0; nf < NF; nf++)
      #pragma unroll
      for (int r = 0; r < 4; r++){
        size_t off = (size_t)(row0 + wr * 128 + mf * 16 + quad * 4 + r) * N + (col0 + wc * (NF * 16) + nf * 16 + c16);
        if (OUTBF16) ((unsigned short*)Cp)[off] = f2bfu(acc[mf][nf][r]);
        else         ((float*)Cp)[off] = acc[mf][nf][r];
      }
}

// ---------------- RoPE (interleaved pairs) on q (softmax scale folded) and k ----------------
__global__ void rope_kernel(const unsigned short* __restrict__ qkv, const float* __restrict__ cosb,
                            const float* __restrict__ sinb, unsigned short* __restrict__ Qo,
                            unsigned short* __restrict__ Ko){
  int idx = blockIdx.x * 256 + threadIdx.x;
  const int NQ = 4096 * 1024;
  if (idx < NQ){
    int m = idx >> 10, p = idx & 1023;
    int h = p >> 5, i = p & 31;
    int s = m & 2047;
    unsigned pr = *reinterpret_cast<const unsigned*>(qkv + (size_t)m * 3072 + h * 64 + 2 * i);
    float t0 = bfu2f((unsigned short)(pr & 0xFFFFu));
    float t1 = bfu2f((unsigned short)(pr >> 16));
    float c = cosb[s * 32 + i], sn = sinb[s * 32 + i];
    const float SC = 0.18033688011112042f;   // (1/8) * log2(e) -> exp2-domain softmax
    float o0 = (t0 * c - t1 * sn) * SC;
    float o1 = (t0 * sn + t1 * c) * SC;
    unsigned ow = (unsigned)f2bfu(o0) | ((unsigned)f2bfu(o1) << 16);
    *reinterpret_cast<unsigned*>(Qo + (size_t)m * 2048 + h * 64 + 2 * i) = ow;
  } else {
    int j = idx - NQ;
    int m = j >> 8, p = j & 255;
    int kvh = p >> 5, i = p & 31;
    int s = m & 2047, b = m >> 11;
    unsigned pr = *reinterpret_cast<const unsigned*>(qkv + (size_t)m * 3072 + 2048 + kvh * 64 + 2 * i);
    float t0 = bfu2f((unsigned short)(pr & 0xFFFFu));
    float t1 = bfu2f((unsigned short)(pr >> 16));
    float c = cosb[s * 32 + i], sn = sinb[s * 32 + i];
    float o0 = t0 * c - t1 * sn;
    float o1 = t0 * sn + t1 * c;
    unsigned ow = (unsigned)f2bfu(o0) | ((unsigned)f2bfu(o1) << 16);
    *reinterpret_cast<unsigned*>(Ko + ((size_t)(b * 8 + kvh) * 2048 + s) * 64 + 2 * i) = ow;
  }
}

// ---------------- V transpose: v_t[b][kvh][d][s] from qkv cols [2560,3072) ----------------
__global__ void vtrans_kernel(const unsigned short* __restrict__ qkv, unsigned short* __restrict__ Vt){
  __shared__ float t[64][65];
  int bh = blockIdx.y;
  int s0 = blockIdx.x * 64;
  int b = bh >> 3, kvh = bh & 7;
  int tid = threadIdx.x;
  #pragma unroll
  for (int it = 0; it < 16; it++){
    int id = it * 256 + tid;
    int sl = id >> 6, d = id & 63;
    unsigned short u = qkv[(size_t)(b * 2048 + s0 + sl) * 3072 + 2560 + kvh * 64 + d];
    t[sl][d] = bfu2f(u);
  }
  __syncthreads();
  #pragma unroll
  for (int it = 0; it < 16; it++){
    int id = it * 256 + tid;
    int dl = id >> 6, sl = id & 63;
    Vt[((size_t)(b * 8 + kvh) * 64 + dl) * 2048 + s0 + sl] = f2bfu(t[sl][dl]);
  }
}

// ---------------- causal GQA flash attention (32x32 swapped, in-register P, no-max) ----------------
// (verified R13; see comments there)
__global__ __launch_bounds__(256) void attn_kernel(const unsigned short* __restrict__ Q,
                                                   const unsigned short* __restrict__ Kt,
                                                   const unsigned short* __restrict__ Vt,
                                                   unsigned short* __restrict__ O){
  __shared__ unsigned short sK[2][64 * 64];
  __shared__ unsigned short sV[2][64 * 64];
  const int tid = threadIdx.x;
  const int l = tid & 63, w = tid >> 6;
  const int q32 = l & 31, hi = l >> 5;
  const int bid = blockIdx.x;
  const int qt = 15 - (bid >> 6);         // largest kv-trip blocks dispatch first (LPT)
  const int bh = bid & 63;
  const int b = bh >> 5, h = bh & 31, kvh = h >> 2;
  const int q0w = qt * 128 + w * 32;
  const int nt = 2 * qt + 2;              // uniform across the block's 4 waves

  const unsigned short* Kb = Kt + (size_t)(b * 8 + kvh) * 2048 * 64;
  const unsigned short* Vb = Vt + (size_t)(b * 8 + kvh) * 64 * 2048;

  auto stage = [&](int kv0, int buf){
    #pragma unroll
    for (int c = 0; c < 2; c++){
      const int rl = w * 16 + c * 8 + (l >> 3);
      const int ce = (((l & 7) ^ (l >> 3)) << 3);
      __builtin_amdgcn_global_load_lds(
        (const __attribute__((address_space(1))) void*)(Kb + (size_t)(kv0 + rl) * 64 + ce),
        (__attribute__((address_space(3))) void*)(&sK[buf][(w * 16 + c * 8) * 64]), 16, 0, 0);
      __builtin_amdgcn_global_load_lds(
        (const __attribute__((address_space(1))) void*)(Vb + (size_t)rl * 2048 + kv0 + ce),
        (__attribute__((address_space(3))) void*)(&sV[buf][(w * 16 + c * 8) * 64]), 16, 0, 0);
    }
  };

  // Q B-frags: lane holds Q[q = q0w+q32][kd*16 + hi*8 + e]
  short8 qv[4];
  {
    const unsigned short* Qp = Q + (size_t)(b * 2048 + q0w + q32) * 2048 + h * 64 + hi * 8;
    #pragma unroll
    for (int kd = 0; kd < 4; kd++) qv[kd] = *reinterpret_cast<const short8*>(Qp + kd * 16);
  }

  const short8 ones = {0x3F80, 0x3F80, 0x3F80, 0x3F80, 0x3F80, 0x3F80, 0x3F80, 0x3F80};

  f32x16 accA = {}, accB = {};   // O cols d = dh*32 + q32; rows q via reg map
  f32x16 accl = {};              // denominator (all cols identical)

  // build one PV A-frag (k-halfslice of 16) from 8 z-regs starting at R0
#define MKAP(Z, R0, AP) { \
    unsigned A_ = cvt_pk_bf16(Z[R0+0], Z[R0+1]); \
    unsigned B_ = cvt_pk_bf16(Z[R0+2], Z[R0+3]); \
    unsigned C_ = cvt_pk_bf16(Z[R0+4], Z[R0+5]); \
    unsigned D_ = cvt_pk_bf16(Z[R0+6], Z[R0+7]); \
    i32x2 s1_ = pl32swap((int)A_, (int)C_); \
    i32x2 s2_ = pl32swap((int)B_, (int)D_); \
    i32x4 q_ = {s1_[0], s2_[0], s1_[1], s2_[1]}; \
    AP = __builtin_bit_cast(short8, q_); \
  }

  stage(0, 0);
  vm_wait<0>();
  __builtin_amdgcn_s_barrier();

  for (int t = 0; t < nt; ++t){
    const int kv0 = t * 64;
    const int buf = t & 1;
    if (t + 1 < nt) stage((t + 1) * 64, buf ^ 1);   // prefetch stays in flight over compute

    const unsigned short* sKc = &sK[buf][0];
    const unsigned short* sVc = &sV[buf][0];

    // ---- S^T = K Q^T (two 32x32 tiles: k 0-31, 32-63) ----
    f32x16 z0 = {}, z1 = {};
    __builtin_amdgcn_s_setprio(1);
    #pragma unroll
    for (int kd = 0; kd < 4; kd++){
      const int u = kd * 2 + hi;
      short8 ak0 = *reinterpret_cast<const short8*>(&sKc[swz64(q32, u)]);
      short8 ak1 = *reinterpret_cast<const short8*>(&sKc[swz64(32 + q32, u)]);
      z0 = __builtin_amdgcn_mfma_f32_32x32x16_bf16(ak0, qv[kd], z0, 0, 0, 0);
      z1 = __builtin_amdgcn_mfma_f32_32x32x16_bf16(ak1, qv[kd], z1, 0, 0, 0);
    }
    __builtin_amdgcn_s_setprio(0);

    // ---- causal mask (wave-uniform branch; near-diagonal + fully-masked tiles) ----
    if (kv0 + 63 > q0w){
      const int qg = q0w + q32;
      #pragma unroll
      for (int r = 0; r < 16; r++){
        const int kr = (r & 3) + 8 * (r >> 2) + 4 * hi;
        if (kv0 + kr > qg)      z0[r] = -1e30f;
        if (kv0 + 32 + kr > qg) z1[r] = -1e30f;
      }
    }

    // ---- P = exp2(S) directly (no max subtraction; lane-local row; masked -> 0) ----
    #pragma unroll
    for (int r = 0; r < 16; r++){
      z0[r] = __builtin_amdgcn_exp2f(z0[r]);
      z1[r] = __builtin_amdgcn_exp2f(z1[r]);
    }

    // ---- PV + ones-denominator, per k-tile (in-register P via cvt_pk + permlane) ----
    short8 apA, apB;
    __builtin_amdgcn_s_setprio(1);
    // kt = 0: k-slices 0,1
    MKAP(z0, 0, apA)
    MKAP(z0, 8, apB)
    accl = __builtin_amdgcn_mfma_f32_32x32x16_bf16(apA, ones, accl, 0, 0, 0);
    accl = __builtin_amdgcn_mfma_f32_32x32x16_bf16(apB, ones, accl, 0, 0, 0);
    {
      short8 bv;
      bv = *reinterpret_cast<const short8*>(&sVc[swz64(q32, 0 * 2 + hi)]);
      accA = __builtin_amdgcn_mfma_f32_32x32x16_bf16(apA, bv, accA, 0, 0, 0);
      bv = *reinterpret_cast<const short8*>(&sVc[swz64(q32, 1 * 2 + hi)]);
      accA = __builtin_amdgcn_mfma_f32_32x32x16_bf16(apB, bv, accA, 0, 0, 0);
      bv = *reinterpret_cast<const short8*>(&sVc[swz64(32 + q32, 0 * 2 + hi)]);
      accB = __builtin_amdgcn_mfma_f32_32x32x16_bf16(apA, bv, accB, 0, 0, 0);
      bv = *reinterpret_cast<const short8*>(&sVc[swz64(32 + q32, 1 * 2 + hi)]);
      accB = __builtin_amdgcn_mfma_f32_32x32x16_bf16(apB, bv, accB, 0, 0, 0);
    }
    // kt = 1: k-slices 2,3
    MKAP(z1, 0, apA)
    MKAP(z1, 8, apB)
    accl = __builtin_amdgcn_mfma_f32_32x32x16_bf16(apA, ones, accl, 0, 0, 0);
    accl = __builtin_amdgcn_mfma_f32_32x32x16_bf16(apB, ones, accl, 0, 0, 0);
    {
      short8 bv;
      bv = *reinterpret_cast<const short8*>(&sVc[swz64(q32, 2 * 2 + hi)]);
      accA = __builtin_amdgcn_mfma_f32_32x32x16_bf16(apA, bv, accA, 0, 0, 0);
      bv = *reinterpret_cast<const short8*>(&sVc[swz64(q32, 3 * 2 + hi)]);
      accA = __builtin_amdgcn_mfma_f32_32x32x16_bf16(apB, bv, accA, 0, 0, 0);
      bv = *reinterpret_cast<const short8*>(&sVc[swz64(32 + q32, 2 * 2 + hi)]);
      accB = __builtin_amdgcn_mfma_f32_32x32x16_bf16(apA, bv, accB, 0, 0, 0);
      bv = *reinterpret_cast<const short8*>(&sVc[swz64(32 + q32, 3 * 2 + hi)]);
      accB = __builtin_amdgcn_mfma_f32_32x32x16_bf16(apB, bv, accB, 0, 0, 0);
    }
    __builtin_amdgcn_s_setprio(0);

    vm_wait<0>();
    __builtin_amdgcn_s_barrier();
  }
#undef MKAP

  // ---- epilogue: normalize rows (accl rows align with acc rows) and store ----
  #pragma unroll
  for (int r = 0; r < 16; r++){
    const float inv = 1.0f / accl[r];
    const int qrow = q0w + (r & 3) + 8 * (r >> 2) + 4 * hi;
    const size_t base = (size_t)(b * 2048 + qrow) * 2048 + h * 64 + q32;
    O[base]      = f2bfu(accA[r] * inv);
    O[base + 32] = f2bfu(accB[r] * inv);
  }
}

extern "C" void kernel_launch(void* const* d_in, const int* in_sizes, int n_in,
                              void* d_out, int out_size, void* d_ws, size_t ws_size,
                              hipStream_t stream){
  (void)in_sizes; (void)n_in; (void)out_size; (void)ws_size;
  const float* x  = (const float*)d_in[0];
  const float* cb = (const float*)d_in[1];
  const float* sb = (const float*)d_in[2];
  const float* Wq = (const float*)d_in[3];
  const float* Wk = (const float*)d_in[4];
  const float* Wv = (const float*)d_in[5];
  const float* Wo = (const float*)d_in[6];
  float* out = (float*)d_out;
  char* ws = (char*)d_ws;

  unsigned short* qkv = (unsigned short*)(ws + 0);           // [4096][3072] bf16
  unsigned short* xb  = (unsigned short*)(ws + 25165824);    // [4096][2048] bf16; reused as attn-out
  unsigned short* wt  = (unsigned short*)(ws + 41943040);    // WqkvT; later WoT
  unsigned short* qb  = (unsigned short*)(ws + 54525952);    // roped q [4096][2048]
  unsigned short* kb  = (unsigned short*)(ws + 71303168);    // roped k [b][kvh][2048][64]
  unsigned short* vt  = (unsigned short*)(ws + 75497472);    // v^T [b][kvh][64][2048]

  dim3 tb(32, 8);
  convx_kernel<<<8192, 256, 0, stream>>>(x, xb, 2097152);
  transpose_conv_kernel<<<dim3(64, 64), tb, 0, stream>>>(Wq, wt, 2048, 2048);
  transpose_conv_kernel<<<dim3(16, 64), tb, 0, stream>>>(Wk, wt + (size_t)2048 * 2048, 2048, 512);
  transpose_conv_kernel<<<dim3(16, 64), tb, 0, stream>>>(Wv, wt + (size_t)2560 * 2048, 2048, 512);
  gemm4p_kernel<3, true><<<256, 512, 0, stream>>>(xb, wt, qkv, 4096, 3072, 2048, 16);
  rope_kernel<<<20480, 256, 0, stream>>>(qkv, cb, sb, qb, kb);
  vtrans_kernel<<<dim3(32, 16), 256, 0, stream>>>(qkv, vt);
  transpose_conv_kernel<<<dim3(64, 64), tb, 0, stream>>>(Wo, wt, 2048, 2048);  // wt now = WoT
  attn_kernel<<<1024, 256, 0, stream>>>(qb, kb, vt, xb);                       // xb now = attn features
  gemm4p_kernel<2, false><<<256, 512, 0, stream>>>(xb, wt, out, 4096, 2048, 2048, 16);
}

// Round 15
// 193.286 us; speedup vs baseline: 1.0138x; 1.0138x over previous
//
#include <hip/hip_runtime.h>
#include <hip/hip_bf16.h>

// Fused attention block: x@Wqkv -> RoPE -> causal GQA flash attention -> @Wo
// bf16 MFMA compute everywhere (2% abs tolerance), f32 I/O.

typedef __attribute__((ext_vector_type(8))) short short8;   // 8 bf16 = 4 VGPR (MFMA A/B frag)
typedef __attribute__((ext_vector_type(4))) float f32x4;    // 16x16 MFMA C/D frag
typedef __attribute__((ext_vector_type(16))) float f32x16;  // 32x32 MFMA C/D frag
typedef __attribute__((ext_vector_type(2))) int i32x2;
typedef __attribute__((ext_vector_type(4))) int i32x4;

__device__ __forceinline__ unsigned short f2bfu(float f){
  unsigned u = __float_as_uint(f);
  u += 0x7FFFu + ((u >> 16) & 1u);      // RNE (no NaNs in this workload)
  return (unsigned short)(u >> 16);
}
__device__ __forceinline__ float bfu2f(unsigned short u){
  return __uint_as_float(((unsigned)u) << 16);
}
// packed f32x2 -> bf16x2 (RNE), single VALU op
__device__ __forceinline__ unsigned cvt_pk_bf16(float lo, float hi){
  unsigned r;
  asm("v_cvt_pk_bf16_f32 %0, %1, %2" : "=v"(r) : "v"(lo), "v"(hi));
  return r;
}
// permlane32_swap: ret[0] = {a_lo, b_lo-of-partner}, ret[1] = {a_hi-of-partner, b_hi}
__device__ __forceinline__ i32x2 pl32swap(int a, int b){
  auto r = __builtin_amdgcn_permlane32_swap(a, b, false, false);
  return __builtin_bit_cast(i32x2, r);
}
// swizzled element offset in a 64-col bf16 row: slot = 16B unit 0..7, XOR row&7
__device__ __forceinline__ int swz64(int row, int slot){
  return row * 64 + (((slot) ^ (row & 7)) << 3);
}
template<int N> __device__ __forceinline__ void vm_wait(){
  if constexpr (N == 10)      asm volatile("s_waitcnt vmcnt(10)" ::: "memory");
  else if constexpr (N == 8)  asm volatile("s_waitcnt vmcnt(8)" ::: "memory");
  else if constexpr (N == 7)  asm volatile("s_waitcnt vmcnt(7)" ::: "memory");
  else if constexpr (N == 6)  asm volatile("s_waitcnt vmcnt(6)" ::: "memory");
  else if constexpr (N == 5)  asm volatile("s_waitcnt vmcnt(5)" ::: "memory");
  else if constexpr (N == 4)  asm volatile("s_waitcnt vmcnt(4)" ::: "memory");
  else if constexpr (N == 3)  asm volatile("s_waitcnt vmcnt(3)" ::: "memory");
  else if constexpr (N == 2)  asm volatile("s_waitcnt vmcnt(2)" ::: "memory");
  else                        asm volatile("s_waitcnt vmcnt(0)" ::: "memory");
}

// ---------------- elementwise f32 -> bf16 ----------------
__global__ void convx_kernel(const float* __restrict__ x, unsigned short* __restrict__ xb, int n4){
  int i = blockIdx.x * blockDim.x + threadIdx.x;
  if (i >= n4) return;
  float4 v = reinterpret_cast<const float4*>(x)[i];
  ushort4 o;
  o.x = f2bfu(v.x); o.y = f2bfu(v.y); o.z = f2bfu(v.z); o.w = f2bfu(v.w);
  reinterpret_cast<ushort4*>(xb)[i] = o;
}

// ---------------- tiled transpose + convert: out[n][k] = (bf16)in[k][n] ----------------
__global__ void transpose_conv_kernel(const float* __restrict__ in, unsigned short* __restrict__ out,
                                      int Min, int Nin){
  __shared__ float t[32][33];
  int c0 = blockIdx.x * 32, r0 = blockIdx.y * 32;
  int tx = threadIdx.x, ty = threadIdx.y;   // 32 x 8
  #pragma unroll
  for (int i = ty; i < 32; i += 8) t[i][tx] = in[(size_t)(r0 + i) * Nin + c0 + tx];
  __syncthreads();
  #pragma unroll
  for (int i = ty; i < 32; i += 8) out[(size_t)(c0 + i) * Min + r0 + tx] = f2bfu(t[tx][i]);
}

// ========= 128 x (NF*64) 4-phase bf16 GEMM, 2 blocks/CU: C = A[M][K] * B^T[N][K] =========
// R11's verified 4-phase schedule, re-parameterized: BM=128, 4 waves (2 wr x 2 wc), per-wave
// 64 x NF*32 output; LDS 80 KB (A 2x16 KB + B 2x2xNF*6 KB... NF=3: 48 KB) -> 2 independent
// blocks/CU (160 KB exactly). Same 8 waves/CU as before but in TWO barrier groups: while one
// block drains lgkmcnt+barrier, the other's MFMAs issue (discriminates serialization-bound
// vs LDS-BW-bound). Staging: per wave per region A=2 + B=NF uniform loads -> per-phase
// vmcnt(2*(2+NF)) leaves <=2 phases of stages in flight; region staged 3 phases before its
// read (R11 flight derivation unchanged). Tail identical to R11.
#define PH4(SLOT,KK,VMW,...) { \
  const unsigned short* sAc = &sA[SLOT][(KK)*4096]; \
  const unsigned short* sBc = &sB[SLOT][(KK)*RB]; \
  short8 afr[4]; short8 bfr[6]; \
  _Pragma("unroll") for (int m_ = 0; m_ < 4; m_++) \
    afr[m_] = *reinterpret_cast<const short8*>(sAc + aOff[m_]); \
  _Pragma("unroll") for (int n_ = 0; n_ < NFR; n_++) \
    bfr[n_] = *reinterpret_cast<const short8*>(sBc + bOff[n_]); \
  __VA_ARGS__; \
  __builtin_amdgcn_s_barrier(); \
  asm volatile("s_waitcnt lgkmcnt(0)" ::: "memory"); \
  __builtin_amdgcn_sched_barrier(0); \
  __builtin_amdgcn_s_setprio(1); \
  _Pragma("unroll") for (int m_ = 0; m_ < 4; m_++){ \
    _Pragma("unroll") for (int n_ = 0; n_ < NFR; n_++){ \
      acc[m_][n_] = __builtin_amdgcn_mfma_f32_16x16x32_bf16(afr[m_], bfr[n_], acc[m_][n_], 0, 0, 0); }} \
  __builtin_amdgcn_s_setprio(0); \
  VMW; \
  __builtin_amdgcn_s_barrier(); \
}

template<int NF, bool OUTBF16>
__global__ __launch_bounds__(256, 2) void gemm4p_kernel(const unsigned short* __restrict__ A,
                                                        const unsigned short* __restrict__ B,
                                                        void* __restrict__ Cp,
                                                        int M, int N, int K, int nbx){
  constexpr int NFR = 2 * NF;                 // n-frags per wave
  constexpr int RB  = NF * 2048;              // elems per B (slot,kk) region (NF*64 rows x 32)
  constexpr int VMS = 2 * (2 + NF);           // per-phase counted wait (2-phase issue window)
  __shared__ unsigned short sA[2][8192];      // 32 KiB  (slot = 2 kk x 128 rows x 32 elems)
  __shared__ unsigned short sB[2][2 * RB];    // NF=3: 48 KiB, NF=2: 32 KiB
  const int tid = threadIdx.x;
  const int l = tid & 63, w = tid >> 6;       // 4 waves
  const int quad = l >> 4, c16 = l & 15;
  // XCD-aware bijective grid swizzle (gridDim.x % 8 == 0)
  const int cpx = (int)gridDim.x >> 3;
  const int id2 = ((int)blockIdx.x & 7) * cpx + ((int)blockIdx.x >> 3);
  const int bx = id2 % nbx, by = id2 / nbx;
  const int row0 = by * 128, col0 = bx * (NF * 64);
  const int wr = w >> 1, wc = w & 1;

  // staging source pointers (pre-swizzled column unit); per-wave: A 2 instr, B NF instr
  const unsigned short* gAp[2];
  const unsigned short* gBp[NF];
  #pragma unroll
  for (int j = 0; j < 2; j++){
    int rl = w * 32 + j * 16 + (l >> 2);
    gAp[j] = A + (size_t)(row0 + rl) * K + ((((l & 3) ^ ((rl >> 1) & 3))) << 3);
  }
  #pragma unroll
  for (int j = 0; j < NF; j++){
    int rl = w * (16 * NF) + j * 16 + (l >> 2);
    gBp[j] = B + (size_t)(col0 + rl) * K + ((((l & 3) ^ ((rl >> 1) & 3))) << 3);
  }

  auto stA = [&](int slot, int kk, int col){
    #pragma unroll
    for (int j = 0; j < 2; j++)
      __builtin_amdgcn_global_load_lds((const __attribute__((address_space(1))) void*)(gAp[j] + col),
          (__attribute__((address_space(3))) void*)(&sA[slot][kk * 4096 + w * 1024 + j * 512]), 16, 0, 0);
  };
  auto stB = [&](int slot, int kk, int col){
    #pragma unroll
    for (int j = 0; j < NF; j++)
      __builtin_amdgcn_global_load_lds((const __attribute__((address_space(1))) void*)(gBp[j] + col),
          (__attribute__((address_space(3))) void*)(&sB[slot][kk * RB + w * (512 * NF) + j * 512]), 16, 0, 0);
  };

  // reader fragment offsets (within a [row][32] k-half region)
  int aOff[4], bOff[6];
  #pragma unroll
  for (int mf = 0; mf < 4; mf++){
    int row = wr * 64 + mf * 16 + c16;
    aOff[mf] = row * 32 + ((quad ^ ((row >> 1) & 3)) << 3);
  }
  #pragma unroll
  for (int nf = 0; nf < NFR; nf++){
    int row = wc * (NF * 32) + nf * 16 + c16;
    bOff[nf] = row * 32 + ((quad ^ ((row >> 1) & 3)) << 3);
  }

  // prologue: regions (0,0),(0,1),(1,0); vmcnt leaves the last 2 regions in flight
  stA(0, 0, 0);  stB(0, 0, 0);
  stA(0, 1, 32); stB(0, 1, 32);
  stA(1, 0, 64); stB(1, 0, 64);
  vm_wait<VMS>();
  __builtin_amdgcn_s_barrier();

  f32x4 acc[4][6] = {};
  const int NI = K >> 7;   // iterations of 2 K-tiles (BK=64)
  #pragma unroll 1
  for (int j = 0; j < NI - 1; ++j){
    const int t1c  = (2 * j + 1) * 64 + 32;  // tile 2j+1, k1
    const int t2c0 = (2 * j + 2) * 64;       // tile 2j+2, k0
    const int t2c1 = t2c0 + 32;
    const int t3c0 = (2 * j + 3) * 64;       // tile 2j+3, k0
    PH4(0,0, vm_wait<VMS>(), stA(1,1,t1c);  stB(1,1,t1c))
    PH4(0,1, vm_wait<VMS>(), stA(0,0,t2c0); stB(0,0,t2c0))
    PH4(1,0, vm_wait<VMS>(), stA(0,1,t2c1); stB(0,1,t2c1))
    PH4(1,1, vm_wait<VMS>(), stA(1,0,t3c0); stB(1,0,t3c0))
  }
  { // peeled last iteration: only the last tile's k1 remains to stage
    const int t1c = K - 32;
    PH4(0,0, vm_wait<VMS>(), stA(1,1,t1c); stB(1,1,t1c))
    PH4(0,1, vm_wait<0>(), ;)
    PH4(1,0, vm_wait<0>(), ;)
    PH4(1,1, (void)0, ;)
  }

  // epilogue
  #pragma unroll
  for (int mf = 0; mf < 4; mf++)
    #pragma unroll
    for (int nf = 0; nf < NFR; nf++)
      #pragma unroll
      for (int r = 0; r < 4; r++){
        size_t off = (size_t)(row0 + wr * 64 + mf * 16 + quad * 4 + r) * N + (col0 + wc * (NF * 32) + nf * 16 + c16);
        if (OUTBF16) ((unsigned short*)Cp)[off] = f2bfu(acc[mf][nf][r]);
        else         ((float*)Cp)[off] = acc[mf][nf][r];
      }
}

// ---------------- RoPE (interleaved pairs) on q (softmax scale folded) and k ----------------
__global__ void rope_kernel(const unsigned short* __restrict__ qkv, const float* __restrict__ cosb,
                            const float* __restrict__ sinb, unsigned short* __restrict__ Qo,
                            unsigned short* __restrict__ Ko){
  int idx = blockIdx.x * 256 + threadIdx.x;
  const int NQ = 4096 * 1024;
  if (idx < NQ){
    int m = idx >> 10, p = idx & 1023;
    int h = p >> 5, i = p & 31;
    int s = m & 2047;
    unsigned pr = *reinterpret_cast<const unsigned*>(qkv + (size_t)m * 3072 + h * 64 + 2 * i);
    float t0 = bfu2f((unsigned short)(pr & 0xFFFFu));
    float t1 = bfu2f((unsigned short)(pr >> 16));
    float c = cosb[s * 32 + i], sn = sinb[s * 32 + i];
    const float SC = 0.18033688011112042f;   // (1/8) * log2(e) -> exp2-domain softmax
    float o0 = (t0 * c - t1 * sn) * SC;
    float o1 = (t0 * sn + t1 * c) * SC;
    unsigned ow = (unsigned)f2bfu(o0) | ((unsigned)f2bfu(o1) << 16);
    *reinterpret_cast<unsigned*>(Qo + (size_t)m * 2048 + h * 64 + 2 * i) = ow;
  } else {
    int j = idx - NQ;
    int m = j >> 8, p = j & 255;
    int kvh = p >> 5, i = p & 31;
    int s = m & 2047, b = m >> 11;
    unsigned pr = *reinterpret_cast<const unsigned*>(qkv + (size_t)m * 3072 + 2048 + kvh * 64 + 2 * i);
    float t0 = bfu2f((unsigned short)(pr & 0xFFFFu));
    float t1 = bfu2f((unsigned short)(pr >> 16));
    float c = cosb[s * 32 + i], sn = sinb[s * 32 + i];
    float o0 = t0 * c - t1 * sn;
    float o1 = t0 * sn + t1 * c;
    unsigned ow = (unsigned)f2bfu(o0) | ((unsigned)f2bfu(o1) << 16);
    *reinterpret_cast<unsigned*>(Ko + ((size_t)(b * 8 + kvh) * 2048 + s) * 64 + 2 * i) = ow;
  }
}

// ---------------- V transpose: v_t[b][kvh][d][s] from qkv cols [2560,3072) ----------------
__global__ void vtrans_kernel(const unsigned short* __restrict__ qkv, unsigned short* __restrict__ Vt){
  __shared__ float t[64][65];
  int bh = blockIdx.y;
  int s0 = blockIdx.x * 64;
  int b = bh >> 3, kvh = bh & 7;
  int tid = threadIdx.x;
  #pragma unroll
  for (int it = 0; it < 16; it++){
    int id = it * 256 + tid;
    int sl = id >> 6, d = id & 63;
    unsigned short u = qkv[(size_t)(b * 2048 + s0 + sl) * 3072 + 2560 + kvh * 64 + d];
    t[sl][d] = bfu2f(u);
  }
  __syncthreads();
  #pragma unroll
  for (int it = 0; it < 16; it++){
    int id = it * 256 + tid;
    int dl = id >> 6, sl = id & 63;
    Vt[((size_t)(b * 8 + kvh) * 64 + dl) * 2048 + s0 + sl] = f2bfu(t[sl][dl]);
  }
}

// ---------------- causal GQA flash attention (32x32 swapped, in-register P, no-max) ----------------
// (verified R13; see comments there)
__global__ __launch_bounds__(256) void attn_kernel(const unsigned short* __restrict__ Q,
                                                   const unsigned short* __restrict__ Kt,
                                                   const unsigned short* __restrict__ Vt,
                                                   unsigned short* __restrict__ O){
  __shared__ unsigned short sK[2][64 * 64];
  __shared__ unsigned short sV[2][64 * 64];
  const int tid = threadIdx.x;
  const int l = tid & 63, w = tid >> 6;
  const int q32 = l & 31, hi = l >> 5;
  const int bid = blockIdx.x;
  const int qt = 15 - (bid >> 6);         // largest kv-trip blocks dispatch first (LPT)
  const int bh = bid & 63;
  const int b = bh >> 5, h = bh & 31, kvh = h >> 2;
  const int q0w = qt * 128 + w * 32;
  const int nt = 2 * qt + 2;              // uniform across the block's 4 waves

  const unsigned short* Kb = Kt + (size_t)(b * 8 + kvh) * 2048 * 64;
  const unsigned short* Vb = Vt + (size_t)(b * 8 + kvh) * 64 * 2048;

  auto stage = [&](int kv0, int buf){
    #pragma unroll
    for (int c = 0; c < 2; c++){
      const int rl = w * 16 + c * 8 + (l >> 3);
      const int ce = (((l & 7) ^ (l >> 3)) << 3);
      __builtin_amdgcn_global_load_lds(
        (const __attribute__((address_space(1))) void*)(Kb + (size_t)(kv0 + rl) * 64 + ce),
        (__attribute__((address_space(3))) void*)(&sK[buf][(w * 16 + c * 8) * 64]), 16, 0, 0);
      __builtin_amdgcn_global_load_lds(
        (const __attribute__((address_space(1))) void*)(Vb + (size_t)rl * 2048 + kv0 + ce),
        (__attribute__((address_space(3))) void*)(&sV[buf][(w * 16 + c * 8) * 64]), 16, 0, 0);
    }
  };

  // Q B-frags: lane holds Q[q = q0w+q32][kd*16 + hi*8 + e]
  short8 qv[4];
  {
    const unsigned short* Qp = Q + (size_t)(b * 2048 + q0w + q32) * 2048 + h * 64 + hi * 8;
    #pragma unroll
    for (int kd = 0; kd < 4; kd++) qv[kd] = *reinterpret_cast<const short8*>(Qp + kd * 16);
  }

  const short8 ones = {0x3F80, 0x3F80, 0x3F80, 0x3F80, 0x3F80, 0x3F80, 0x3F80, 0x3F80};

  f32x16 accA = {}, accB = {};   // O cols d = dh*32 + q32; rows q via reg map
  f32x16 accl = {};              // denominator (all cols identical)

  // build one PV A-frag (k-halfslice of 16) from 8 z-regs starting at R0
#define MKAP(Z, R0, AP) { \
    unsigned A_ = cvt_pk_bf16(Z[R0+0], Z[R0+1]); \
    unsigned B_ = cvt_pk_bf16(Z[R0+2], Z[R0+3]); \
    unsigned C_ = cvt_pk_bf16(Z[R0+4], Z[R0+5]); \
    unsigned D_ = cvt_pk_bf16(Z[R0+6], Z[R0+7]); \
    i32x2 s1_ = pl32swap((int)A_, (int)C_); \
    i32x2 s2_ = pl32swap((int)B_, (int)D_); \
    i32x4 q_ = {s1_[0], s2_[0], s1_[1], s2_[1]}; \
    AP = __builtin_bit_cast(short8, q_); \
  }

  stage(0, 0);
  vm_wait<0>();
  __builtin_amdgcn_s_barrier();

  for (int t = 0; t < nt; ++t){
    const int kv0 = t * 64;
    const int buf = t & 1;
    if (t + 1 < nt) stage((t + 1) * 64, buf ^ 1);   // prefetch stays in flight over compute

    const unsigned short* sKc = &sK[buf][0];
    const unsigned short* sVc = &sV[buf][0];

    // ---- S^T = K Q^T (two 32x32 tiles: k 0-31, 32-63) ----
    f32x16 z0 = {}, z1 = {};
    __builtin_amdgcn_s_setprio(1);
    #pragma unroll
    for (int kd = 0; kd < 4; kd++){
      const int u = kd * 2 + hi;
      short8 ak0 = *reinterpret_cast<const short8*>(&sKc[swz64(q32, u)]);
      short8 ak1 = *reinterpret_cast<const short8*>(&sKc[swz64(32 + q32, u)]);
      z0 = __builtin_amdgcn_mfma_f32_32x32x16_bf16(ak0, qv[kd], z0, 0, 0, 0);
      z1 = __builtin_amdgcn_mfma_f32_32x32x16_bf16(ak1, qv[kd], z1, 0, 0, 0);
    }
    __builtin_amdgcn_s_setprio(0);

    // ---- causal mask (wave-uniform branch; near-diagonal + fully-masked tiles) ----
    if (kv0 + 63 > q0w){
      const int qg = q0w + q32;
      #pragma unroll
      for (int r = 0; r < 16; r++){
        const int kr = (r & 3) + 8 * (r >> 2) + 4 * hi;
        if (kv0 + kr > qg)      z0[r] = -1e30f;
        if (kv0 + 32 + kr > qg) z1[r] = -1e30f;
      }
    }

    // ---- P = exp2(S) directly (no max subtraction; lane-local row; masked -> 0) ----
    #pragma unroll
    for (int r = 0; r < 16; r++){
      z0[r] = __builtin_amdgcn_exp2f(z0[r]);
      z1[r] = __builtin_amdgcn_exp2f(z1[r]);
    }

    // ---- PV + ones-denominator, per k-tile (in-register P via cvt_pk + permlane) ----
    short8 apA, apB;
    __builtin_amdgcn_s_setprio(1);
    // kt = 0: k-slices 0,1
    MKAP(z0, 0, apA)
    MKAP(z0, 8, apB)
    accl = __builtin_amdgcn_mfma_f32_32x32x16_bf16(apA, ones, accl, 0, 0, 0);
    accl = __builtin_amdgcn_mfma_f32_32x32x16_bf16(apB, ones, accl, 0, 0, 0);
    {
      short8 bv;
      bv = *reinterpret_cast<const short8*>(&sVc[swz64(q32, 0 * 2 + hi)]);
      accA = __builtin_amdgcn_mfma_f32_32x32x16_bf16(apA, bv, accA, 0, 0, 0);
      bv = *reinterpret_cast<const short8*>(&sVc[swz64(q32, 1 * 2 + hi)]);
      accA = __builtin_amdgcn_mfma_f32_32x32x16_bf16(apB, bv, accA, 0, 0, 0);
      bv = *reinterpret_cast<const short8*>(&sVc[swz64(32 + q32, 0 * 2 + hi)]);
      accB = __builtin_amdgcn_mfma_f32_32x32x16_bf16(apA, bv, accB, 0, 0, 0);
      bv = *reinterpret_cast<const short8*>(&sVc[swz64(32 + q32, 1 * 2 + hi)]);
      accB = __builtin_amdgcn_mfma_f32_32x32x16_bf16(apB, bv, accB, 0, 0, 0);
    }
    // kt = 1: k-slices 2,3
    MKAP(z1, 0, apA)
    MKAP(z1, 8, apB)
    accl = __builtin_amdgcn_mfma_f32_32x32x16_bf16(apA, ones, accl, 0, 0, 0);
    accl = __builtin_amdgcn_mfma_f32_32x32x16_bf16(apB, ones, accl, 0, 0, 0);
    {
      short8 bv;
      bv = *reinterpret_cast<const short8*>(&sVc[swz64(q32, 2 * 2 + hi)]);
      accA = __builtin_amdgcn_mfma_f32_32x32x16_bf16(apA, bv, accA, 0, 0, 0);
      bv = *reinterpret_cast<const short8*>(&sVc[swz64(q32, 3 * 2 + hi)]);
      accA = __builtin_amdgcn_mfma_f32_32x32x16_bf16(apB, bv, accA, 0, 0, 0);
      bv = *reinterpret_cast<const short8*>(&sVc[swz64(32 + q32, 2 * 2 + hi)]);
      accB = __builtin_amdgcn_mfma_f32_32x32x16_bf16(apA, bv, accB, 0, 0, 0);
      bv = *reinterpret_cast<const short8*>(&sVc[swz64(32 + q32, 3 * 2 + hi)]);
      accB = __builtin_amdgcn_mfma_f32_32x32x16_bf16(apB, bv, accB, 0, 0, 0);
    }
    __builtin_amdgcn_s_setprio(0);

    vm_wait<0>();
    __builtin_amdgcn_s_barrier();
  }
#undef MKAP

  // ---- epilogue: normalize rows (accl rows align with acc rows) and store ----
  #pragma unroll
  for (int r = 0; r < 16; r++){
    const float inv = 1.0f / accl[r];
    const int qrow = q0w + (r & 3) + 8 * (r >> 2) + 4 * hi;
    const size_t base = (size_t)(b * 2048 + qrow) * 2048 + h * 64 + q32;
    O[base]      = f2bfu(accA[r] * inv);
    O[base + 32] = f2bfu(accB[r] * inv);
  }
}

extern "C" void kernel_launch(void* const* d_in, const int* in_sizes, int n_in,
                              void* d_out, int out_size, void* d_ws, size_t ws_size,
                              hipStream_t stream){
  (void)in_sizes; (void)n_in; (void)out_size; (void)ws_size;
  const float* x  = (const float*)d_in[0];
  const float* cb = (const float*)d_in[1];
  const float* sb = (const float*)d_in[2];
  const float* Wq = (const float*)d_in[3];
  const float* Wk = (const float*)d_in[4];
  const float* Wv = (const float*)d_in[5];
  const float* Wo = (const float*)d_in[6];
  float* out = (float*)d_out;
  char* ws = (char*)d_ws;

  unsigned short* qkv = (unsigned short*)(ws + 0);           // [4096][3072] bf16
  unsigned short* xb  = (unsigned short*)(ws + 25165824);    // [4096][2048] bf16; reused as attn-out
  unsigned short* wt  = (unsigned short*)(ws + 41943040);    // WqkvT; later WoT
  unsigned short* qb  = (unsigned short*)(ws + 54525952);    // roped q [4096][2048]
  unsigned short* kb  = (unsigned short*)(ws + 71303168);    // roped k [b][kvh][2048][64]
  unsigned short* vt  = (unsigned short*)(ws + 75497472);    // v^T [b][kvh][64][2048]

  dim3 tb(32, 8);
  convx_kernel<<<8192, 256, 0, stream>>>(x, xb, 2097152);
  transpose_conv_kernel<<<dim3(64, 64), tb, 0, stream>>>(Wq, wt, 2048, 2048);
  transpose_conv_kernel<<<dim3(16, 64), tb, 0, stream>>>(Wk, wt + (size_t)2048 * 2048, 2048, 512);
  transpose_conv_kernel<<<dim3(16, 64), tb, 0, stream>>>(Wv, wt + (size_t)2560 * 2048, 2048, 512);
  gemm4p_kernel<3, true><<<512, 256, 0, stream>>>(xb, wt, qkv, 4096, 3072, 2048, 16);
  rope_kernel<<<20480, 256, 0, stream>>>(qkv, cb, sb, qb, kb);
  vtrans_kernel<<<dim3(32, 16), 256, 0, stream>>>(qkv, vt);
  transpose_conv_kernel<<<dim3(64, 64), tb, 0, stream>>>(Wo, wt, 2048, 2048);  // wt now = WoT
  attn_kernel<<<1024, 256, 0, stream>>>(qb, kb, vt, xb);                       // xb now = attn features
  gemm4p_kernel<2, false><<<512, 256, 0, stream>>>(xb, wt, out, 4096, 2048, 2048, 16);
}

// Round 16
// 188.399 us; speedup vs baseline: 1.0401x; 1.0259x over previous
//
#include <hip/hip_runtime.h>
#include <hip/hip_bf16.h>

// Fused attention block: x@Wqkv -> RoPE -> causal GQA flash attention -> @Wo
// bf16 MFMA compute everywhere (2% abs tolerance), f32 I/O.

typedef __attribute__((ext_vector_type(8))) short short8;   // 8 bf16 = 4 VGPR (MFMA A/B frag)
typedef __attribute__((ext_vector_type(4))) float f32x4;    // 16x16 MFMA C/D frag
typedef __attribute__((ext_vector_type(16))) float f32x16;  // 32x32 MFMA C/D frag
typedef __attribute__((ext_vector_type(2))) int i32x2;
typedef __attribute__((ext_vector_type(4))) int i32x4;

__device__ __forceinline__ unsigned short f2bfu(float f){
  unsigned u = __float_as_uint(f);
  u += 0x7FFFu + ((u >> 16) & 1u);      // RNE (no NaNs in this workload)
  return (unsigned short)(u >> 16);
}
__device__ __forceinline__ float bfu2f(unsigned short u){
  return __uint_as_float(((unsigned)u) << 16);
}
// packed f32x2 -> bf16x2 (RNE), single VALU op
__device__ __forceinline__ unsigned cvt_pk_bf16(float lo, float hi){
  unsigned r;
  asm("v_cvt_pk_bf16_f32 %0, %1, %2" : "=v"(r) : "v"(lo), "v"(hi));
  return r;
}
// permlane32_swap: ret[0] = {a_lo, b_lo-of-partner}, ret[1] = {a_hi-of-partner, b_hi}
__device__ __forceinline__ i32x2 pl32swap(int a, int b){
  auto r = __builtin_amdgcn_permlane32_swap(a, b, false, false);
  return __builtin_bit_cast(i32x2, r);
}
// swizzled element offset in a 64-col bf16 row: slot = 16B unit 0..7, XOR row&7
__device__ __forceinline__ int swz64(int row, int slot){
  return row * 64 + (((slot) ^ (row & 7)) << 3);
}
template<int N> __device__ __forceinline__ void vm_wait(){
  if constexpr (N == 10)      asm volatile("s_waitcnt vmcnt(10)" ::: "memory");
  else if constexpr (N == 8)  asm volatile("s_waitcnt vmcnt(8)" ::: "memory");
  else if constexpr (N == 7)  asm volatile("s_waitcnt vmcnt(7)" ::: "memory");
  else if constexpr (N == 6)  asm volatile("s_waitcnt vmcnt(6)" ::: "memory");
  else if constexpr (N == 5)  asm volatile("s_waitcnt vmcnt(5)" ::: "memory");
  else if constexpr (N == 4)  asm volatile("s_waitcnt vmcnt(4)" ::: "memory");
  else if constexpr (N == 3)  asm volatile("s_waitcnt vmcnt(3)" ::: "memory");
  else if constexpr (N == 2)  asm volatile("s_waitcnt vmcnt(2)" ::: "memory");
  else                        asm volatile("s_waitcnt vmcnt(0)" ::: "memory");
}

// ---------------- elementwise f32 -> bf16 ----------------
__global__ void convx_kernel(const float* __restrict__ x, unsigned short* __restrict__ xb, int n4){
  int i = blockIdx.x * blockDim.x + threadIdx.x;
  if (i >= n4) return;
  float4 v = reinterpret_cast<const float4*>(x)[i];
  ushort4 o;
  o.x = f2bfu(v.x); o.y = f2bfu(v.y); o.z = f2bfu(v.z); o.w = f2bfu(v.w);
  reinterpret_cast<ushort4*>(xb)[i] = o;
}

// ---------------- tiled transpose + convert: out[n][k] = (bf16)in[k][n] ----------------
__global__ void transpose_conv_kernel(const float* __restrict__ in, unsigned short* __restrict__ out,
                                      int Min, int Nin){
  __shared__ float t[32][33];
  int c0 = blockIdx.x * 32, r0 = blockIdx.y * 32;
  int tx = threadIdx.x, ty = threadIdx.y;   // 32 x 8
  #pragma unroll
  for (int i = ty; i < 32; i += 8) t[i][tx] = in[(size_t)(r0 + i) * Nin + c0 + tx];
  __syncthreads();
  #pragma unroll
  for (int i = ty; i < 32; i += 8) out[(size_t)(c0 + i) * Min + r0 + tx] = f2bfu(t[tx][i]);
}

// ========= 128 x (NF*64) 4-phase bf16 GEMM, 2 blocks/CU: C = A[M][K] * B^T[N][K] =========
// (verified R15; see comments there)
#define PH4(SLOT,KK,VMW,...) { \
  const unsigned short* sAc = &sA[SLOT][(KK)*4096]; \
  const unsigned short* sBc = &sB[SLOT][(KK)*RB]; \
  short8 afr[4]; short8 bfr[6]; \
  _Pragma("unroll") for (int m_ = 0; m_ < 4; m_++) \
    afr[m_] = *reinterpret_cast<const short8*>(sAc + aOff[m_]); \
  _Pragma("unroll") for (int n_ = 0; n_ < NFR; n_++) \
    bfr[n_] = *reinterpret_cast<const short8*>(sBc + bOff[n_]); \
  __VA_ARGS__; \
  __builtin_amdgcn_s_barrier(); \
  asm volatile("s_waitcnt lgkmcnt(0)" ::: "memory"); \
  __builtin_amdgcn_sched_barrier(0); \
  __builtin_amdgcn_s_setprio(1); \
  _Pragma("unroll") for (int m_ = 0; m_ < 4; m_++){ \
    _Pragma("unroll") for (int n_ = 0; n_ < NFR; n_++){ \
      acc[m_][n_] = __builtin_amdgcn_mfma_f32_16x16x32_bf16(afr[m_], bfr[n_], acc[m_][n_], 0, 0, 0); }} \
  __builtin_amdgcn_s_setprio(0); \
  VMW; \
  __builtin_amdgcn_s_barrier(); \
}

template<int NF, bool OUTBF16>
__global__ __launch_bounds__(256, 2) void gemm4p_kernel(const unsigned short* __restrict__ A,
                                                        const unsigned short* __restrict__ B,
                                                        void* __restrict__ Cp,
                                                        int M, int N, int K, int nbx){
  constexpr int NFR = 2 * NF;                 // n-frags per wave
  constexpr int RB  = NF * 2048;              // elems per B (slot,kk) region (NF*64 rows x 32)
  constexpr int VMS = 2 * (2 + NF);           // per-phase counted wait (2-phase issue window)
  __shared__ unsigned short sA[2][8192];      // 32 KiB  (slot = 2 kk x 128 rows x 32 elems)
  __shared__ unsigned short sB[2][2 * RB];    // NF=3: 48 KiB, NF=2: 32 KiB
  const int tid = threadIdx.x;
  const int l = tid & 63, w = tid >> 6;       // 4 waves
  const int quad = l >> 4, c16 = l & 15;
  // XCD-aware bijective grid swizzle (gridDim.x % 8 == 0)
  const int cpx = (int)gridDim.x >> 3;
  const int id2 = ((int)blockIdx.x & 7) * cpx + ((int)blockIdx.x >> 3);
  const int bx = id2 % nbx, by = id2 / nbx;
  const int row0 = by * 128, col0 = bx * (NF * 64);
  const int wr = w >> 1, wc = w & 1;

  // staging source pointers (pre-swizzled column unit); per-wave: A 2 instr, B NF instr
  const unsigned short* gAp[2];
  const unsigned short* gBp[NF];
  #pragma unroll
  for (int j = 0; j < 2; j++){
    int rl = w * 32 + j * 16 + (l >> 2);
    gAp[j] = A + (size_t)(row0 + rl) * K + ((((l & 3) ^ ((rl >> 1) & 3))) << 3);
  }
  #pragma unroll
  for (int j = 0; j < NF; j++){
    int rl = w * (16 * NF) + j * 16 + (l >> 2);
    gBp[j] = B + (size_t)(col0 + rl) * K + ((((l & 3) ^ ((rl >> 1) & 3))) << 3);
  }

  auto stA = [&](int slot, int kk, int col){
    #pragma unroll
    for (int j = 0; j < 2; j++)
      __builtin_amdgcn_global_load_lds((const __attribute__((address_space(1))) void*)(gAp[j] + col),
          (__attribute__((address_space(3))) void*)(&sA[slot][kk * 4096 + w * 1024 + j * 512]), 16, 0, 0);
  };
  auto stB = [&](int slot, int kk, int col){
    #pragma unroll
    for (int j = 0; j < NF; j++)
      __builtin_amdgcn_global_load_lds((const __attribute__((address_space(1))) void*)(gBp[j] + col),
          (__attribute__((address_space(3))) void*)(&sB[slot][kk * RB + w * (512 * NF) + j * 512]), 16, 0, 0);
  };

  // reader fragment offsets (within a [row][32] k-half region)
  int aOff[4], bOff[6];
  #pragma unroll
  for (int mf = 0; mf < 4; mf++){
    int row = wr * 64 + mf * 16 + c16;
    aOff[mf] = row * 32 + ((quad ^ ((row >> 1) & 3)) << 3);
  }
  #pragma unroll
  for (int nf = 0; nf < NFR; nf++){
    int row = wc * (NF * 32) + nf * 16 + c16;
    bOff[nf] = row * 32 + ((quad ^ ((row >> 1) & 3)) << 3);
  }

  // prologue: regions (0,0),(0,1),(1,0); vmcnt leaves the last 2 regions in flight
  stA(0, 0, 0);  stB(0, 0, 0);
  stA(0, 1, 32); stB(0, 1, 32);
  stA(1, 0, 64); stB(1, 0, 64);
  vm_wait<VMS>();
  __builtin_amdgcn_s_barrier();

  f32x4 acc[4][6] = {};
  const int NI = K >> 7;   // iterations of 2 K-tiles (BK=64)
  #pragma unroll 1
  for (int j = 0; j < NI - 1; ++j){
    const int t1c  = (2 * j + 1) * 64 + 32;  // tile 2j+1, k1
    const int t2c0 = (2 * j + 2) * 64;       // tile 2j+2, k0
    const int t2c1 = t2c0 + 32;
    const int t3c0 = (2 * j + 3) * 64;       // tile 2j+3, k0
    PH4(0,0, vm_wait<VMS>(), stA(1,1,t1c);  stB(1,1,t1c))
    PH4(0,1, vm_wait<VMS>(), stA(0,0,t2c0); stB(0,0,t2c0))
    PH4(1,0, vm_wait<VMS>(), stA(0,1,t2c1); stB(0,1,t2c1))
    PH4(1,1, vm_wait<VMS>(), stA(1,0,t3c0); stB(1,0,t3c0))
  }
  { // peeled last iteration: only the last tile's k1 remains to stage
    const int t1c = K - 32;
    PH4(0,0, vm_wait<VMS>(), stA(1,1,t1c); stB(1,1,t1c))
    PH4(0,1, vm_wait<0>(), ;)
    PH4(1,0, vm_wait<0>(), ;)
    PH4(1,1, (void)0, ;)
  }

  // epilogue
  #pragma unroll
  for (int mf = 0; mf < 4; mf++)
    #pragma unroll
    for (int nf = 0; nf < NFR; nf++)
      #pragma unroll
      for (int r = 0; r < 4; r++){
        size_t off = (size_t)(row0 + wr * 64 + mf * 16 + quad * 4 + r) * N + (col0 + wc * (NF * 32) + nf * 16 + c16);
        if (OUTBF16) ((unsigned short*)Cp)[off] = f2bfu(acc[mf][nf][r]);
        else         ((float*)Cp)[off] = acc[mf][nf][r];
      }
}

// ---------------- RoPE (interleaved pairs) on q (softmax scale folded) and k ----------------
__global__ void rope_kernel(const unsigned short* __restrict__ qkv, const float* __restrict__ cosb,
                            const float* __restrict__ sinb, unsigned short* __restrict__ Qo,
                            unsigned short* __restrict__ Ko){
  int idx = blockIdx.x * 256 + threadIdx.x;
  const int NQ = 4096 * 1024;
  if (idx < NQ){
    int m = idx >> 10, p = idx & 1023;
    int h = p >> 5, i = p & 31;
    int s = m & 2047;
    unsigned pr = *reinterpret_cast<const unsigned*>(qkv + (size_t)m * 3072 + h * 64 + 2 * i);
    float t0 = bfu2f((unsigned short)(pr & 0xFFFFu));
    float t1 = bfu2f((unsigned short)(pr >> 16));
    float c = cosb[s * 32 + i], sn = sinb[s * 32 + i];
    const float SC = 0.18033688011112042f;   // (1/8) * log2(e) -> exp2-domain softmax
    float o0 = (t0 * c - t1 * sn) * SC;
    float o1 = (t0 * sn + t1 * c) * SC;
    unsigned ow = (unsigned)f2bfu(o0) | ((unsigned)f2bfu(o1) << 16);
    *reinterpret_cast<unsigned*>(Qo + (size_t)m * 2048 + h * 64 + 2 * i) = ow;
  } else {
    int j = idx - NQ;
    int m = j >> 8, p = j & 255;
    int kvh = p >> 5, i = p & 31;
    int s = m & 2047, b = m >> 11;
    unsigned pr = *reinterpret_cast<const unsigned*>(qkv + (size_t)m * 3072 + 2048 + kvh * 64 + 2 * i);
    float t0 = bfu2f((unsigned short)(pr & 0xFFFFu));
    float t1 = bfu2f((unsigned short)(pr >> 16));
    float c = cosb[s * 32 + i], sn = sinb[s * 32 + i];
    float o0 = t0 * c - t1 * sn;
    float o1 = t0 * sn + t1 * c;
    unsigned ow = (unsigned)f2bfu(o0) | ((unsigned)f2bfu(o1) << 16);
    *reinterpret_cast<unsigned*>(Ko + ((size_t)(b * 8 + kvh) * 2048 + s) * 64 + 2 * i) = ow;
  }
}

// ---------------- V transpose: v_t[b][kvh][d][s] from qkv cols [2560,3072) ----------------
__global__ void vtrans_kernel(const unsigned short* __restrict__ qkv, unsigned short* __restrict__ Vt){
  __shared__ float t[64][65];
  int bh = blockIdx.y;
  int s0 = blockIdx.x * 64;
  int b = bh >> 3, kvh = bh & 7;
  int tid = threadIdx.x;
  #pragma unroll
  for (int it = 0; it < 16; it++){
    int id = it * 256 + tid;
    int sl = id >> 6, d = id & 63;
    unsigned short u = qkv[(size_t)(b * 2048 + s0 + sl) * 3072 + 2560 + kvh * 64 + d];
    t[sl][d] = bfu2f(u);
  }
  __syncthreads();
  #pragma unroll
  for (int it = 0; it < 16; it++){
    int id = it * 256 + tid;
    int dl = id >> 6, sl = id & 63;
    Vt[((size_t)(b * 8 + kvh) * 64 + dl) * 2048 + s0 + sl] = f2bfu(t[sl][dl]);
  }
}

// ---------------- causal GQA flash attention (32x32 swapped, in-register P, no-max) ----------------
// (verified R13) + __launch_bounds__(256, 4): VGPR 80 / LDS 32 KB allow 4 blocks/CU (16
// waves) but measured occupancy sat at 8 waves; declare min 4 waves/EU to claim residency.
__global__ __launch_bounds__(256, 4) void attn_kernel(const unsigned short* __restrict__ Q,
                                                      const unsigned short* __restrict__ Kt,
                                                      const unsigned short* __restrict__ Vt,
                                                      unsigned short* __restrict__ O){
  __shared__ unsigned short sK[2][64 * 64];
  __shared__ unsigned short sV[2][64 * 64];
  const int tid = threadIdx.x;
  const int l = tid & 63, w = tid >> 6;
  const int q32 = l & 31, hi = l >> 5;
  const int bid = blockIdx.x;
  const int qt = 15 - (bid >> 6);         // largest kv-trip blocks dispatch first (LPT)
  const int bh = bid & 63;
  const int b = bh >> 5, h = bh & 31, kvh = h >> 2;
  const int q0w = qt * 128 + w * 32;
  const int nt = 2 * qt + 2;              // uniform across the block's 4 waves

  const unsigned short* Kb = Kt + (size_t)(b * 8 + kvh) * 2048 * 64;
  const unsigned short* Vb = Vt + (size_t)(b * 8 + kvh) * 64 * 2048;

  auto stage = [&](int kv0, int buf){
    #pragma unroll
    for (int c = 0; c < 2; c++){
      const int rl = w * 16 + c * 8 + (l >> 3);
      const int ce = (((l & 7) ^ (l >> 3)) << 3);
      __builtin_amdgcn_global_load_lds(
        (const __attribute__((address_space(1))) void*)(Kb + (size_t)(kv0 + rl) * 64 + ce),
        (__attribute__((address_space(3))) void*)(&sK[buf][(w * 16 + c * 8) * 64]), 16, 0, 0);
      __builtin_amdgcn_global_load_lds(
        (const __attribute__((address_space(1))) void*)(Vb + (size_t)rl * 2048 + kv0 + ce),
        (__attribute__((address_space(3))) void*)(&sV[buf][(w * 16 + c * 8) * 64]), 16, 0, 0);
    }
  };

  // Q B-frags: lane holds Q[q = q0w+q32][kd*16 + hi*8 + e]
  short8 qv[4];
  {
    const unsigned short* Qp = Q + (size_t)(b * 2048 + q0w + q32) * 2048 + h * 64 + hi * 8;
    #pragma unroll
    for (int kd = 0; kd < 4; kd++) qv[kd] = *reinterpret_cast<const short8*>(Qp + kd * 16);
  }

  const short8 ones = {0x3F80, 0x3F80, 0x3F80, 0x3F80, 0x3F80, 0x3F80, 0x3F80, 0x3F80};

  f32x16 accA = {}, accB = {};   // O cols d = dh*32 + q32; rows q via reg map
  f32x16 accl = {};              // denominator (all cols identical)

  // build one PV A-frag (k-halfslice of 16) from 8 z-regs starting at R0
#define MKAP(Z, R0, AP) { \
    unsigned A_ = cvt_pk_bf16(Z[R0+0], Z[R0+1]); \
    unsigned B_ = cvt_pk_bf16(Z[R0+2], Z[R0+3]); \
    unsigned C_ = cvt_pk_bf16(Z[R0+4], Z[R0+5]); \
    unsigned D_ = cvt_pk_bf16(Z[R0+6], Z[R0+7]); \
    i32x2 s1_ = pl32swap((int)A_, (int)C_); \
    i32x2 s2_ = pl32swap((int)B_, (int)D_); \
    i32x4 q_ = {s1_[0], s2_[0], s1_[1], s2_[1]}; \
    AP = __builtin_bit_cast(short8, q_); \
  }

  stage(0, 0);
  vm_wait<0>();
  __builtin_amdgcn_s_barrier();

  for (int t = 0; t < nt; ++t){
    const int kv0 = t * 64;
    const int buf = t & 1;
    if (t + 1 < nt) stage((t + 1) * 64, buf ^ 1);   // prefetch stays in flight over compute

    const unsigned short* sKc = &sK[buf][0];
    const unsigned short* sVc = &sV[buf][0];

    // ---- S^T = K Q^T (two 32x32 tiles: k 0-31, 32-63) ----
    f32x16 z0 = {}, z1 = {};
    __builtin_amdgcn_s_setprio(1);
    #pragma unroll
    for (int kd = 0; kd < 4; kd++){
      const int u = kd * 2 + hi;
      short8 ak0 = *reinterpret_cast<const short8*>(&sKc[swz64(q32, u)]);
      short8 ak1 = *reinterpret_cast<const short8*>(&sKc[swz64(32 + q32, u)]);
      z0 = __builtin_amdgcn_mfma_f32_32x32x16_bf16(ak0, qv[kd], z0, 0, 0, 0);
      z1 = __builtin_amdgcn_mfma_f32_32x32x16_bf16(ak1, qv[kd], z1, 0, 0, 0);
    }
    __builtin_amdgcn_s_setprio(0);

    // ---- causal mask (wave-uniform branch; near-diagonal + fully-masked tiles) ----
    if (kv0 + 63 > q0w){
      const int qg = q0w + q32;
      #pragma unroll
      for (int r = 0; r < 16; r++){
        const int kr = (r & 3) + 8 * (r >> 2) + 4 * hi;
        if (kv0 + kr > qg)      z0[r] = -1e30f;
        if (kv0 + 32 + kr > qg) z1[r] = -1e30f;
      }
    }

    // ---- P = exp2(S) directly (no max subtraction; lane-local row; masked -> 0) ----
    #pragma unroll
    for (int r = 0; r < 16; r++){
      z0[r] = __builtin_amdgcn_exp2f(z0[r]);
      z1[r] = __builtin_amdgcn_exp2f(z1[r]);
    }

    // ---- PV + ones-denominator, per k-tile (in-register P via cvt_pk + permlane) ----
    short8 apA, apB;
    __builtin_amdgcn_s_setprio(1);
    // kt = 0: k-slices 0,1
    MKAP(z0, 0, apA)
    MKAP(z0, 8, apB)
    accl = __builtin_amdgcn_mfma_f32_32x32x16_bf16(apA, ones, accl, 0, 0, 0);
    accl = __builtin_amdgcn_mfma_f32_32x32x16_bf16(apB, ones, accl, 0, 0, 0);
    {
      short8 bv;
      bv = *reinterpret_cast<const short8*>(&sVc[swz64(q32, 0 * 2 + hi)]);
      accA = __builtin_amdgcn_mfma_f32_32x32x16_bf16(apA, bv, accA, 0, 0, 0);
      bv = *reinterpret_cast<const short8*>(&sVc[swz64(q32, 1 * 2 + hi)]);
      accA = __builtin_amdgcn_mfma_f32_32x32x16_bf16(apB, bv, accA, 0, 0, 0);
      bv = *reinterpret_cast<const short8*>(&sVc[swz64(32 + q32, 0 * 2 + hi)]);
      accB = __builtin_amdgcn_mfma_f32_32x32x16_bf16(apA, bv, accB, 0, 0, 0);
      bv = *reinterpret_cast<const short8*>(&sVc[swz64(32 + q32, 1 * 2 + hi)]);
      accB = __builtin_amdgcn_mfma_f32_32x32x16_bf16(apB, bv, accB, 0, 0, 0);
    }
    // kt = 1: k-slices 2,3
    MKAP(z1, 0, apA)
    MKAP(z1, 8, apB)
    accl = __builtin_amdgcn_mfma_f32_32x32x16_bf16(apA, ones, accl, 0, 0, 0);
    accl = __builtin_amdgcn_mfma_f32_32x32x16_bf16(apB, ones, accl, 0, 0, 0);
    {
      short8 bv;
      bv = *reinterpret_cast<const short8*>(&sVc[swz64(q32, 2 * 2 + hi)]);
      accA = __builtin_amdgcn_mfma_f32_32x32x16_bf16(apA, bv, accA, 0, 0, 0);
      bv = *reinterpret_cast<const short8*>(&sVc[swz64(q32, 3 * 2 + hi)]);
      accA = __builtin_amdgcn_mfma_f32_32x32x16_bf16(apB, bv, accA, 0, 0, 0);
      bv = *reinterpret_cast<const short8*>(&sVc[swz64(32 + q32, 2 * 2 + hi)]);
      accB = __builtin_amdgcn_mfma_f32_32x32x16_bf16(apA, bv, accB, 0, 0, 0);
      bv = *reinterpret_cast<const short8*>(&sVc[swz64(32 + q32, 3 * 2 + hi)]);
      accB = __builtin_amdgcn_mfma_f32_32x32x16_bf16(apB, bv, accB, 0, 0, 0);
    }
    __builtin_amdgcn_s_setprio(0);

    vm_wait<0>();
    __builtin_amdgcn_s_barrier();
  }
#undef MKAP

  // ---- epilogue: normalize rows (accl rows align with acc rows) and store ----
  #pragma unroll
  for (int r = 0; r < 16; r++){
    const float inv = 1.0f / accl[r];
    const int qrow = q0w + (r & 3) + 8 * (r >> 2) + 4 * hi;
    const size_t base = (size_t)(b * 2048 + qrow) * 2048 + h * 64 + q32;
    O[base]      = f2bfu(accA[r] * inv);
    O[base + 32] = f2bfu(accB[r] * inv);
  }
}

extern "C" void kernel_launch(void* const* d_in, const int* in_sizes, int n_in,
                              void* d_out, int out_size, void* d_ws, size_t ws_size,
                              hipStream_t stream){
  (void)in_sizes; (void)n_in; (void)out_size; (void)ws_size;
  const float* x  = (const float*)d_in[0];
  const float* cb = (const float*)d_in[1];
  const float* sb = (const float*)d_in[2];
  const float* Wq = (const float*)d_in[3];
  const float* Wk = (const float*)d_in[4];
  const float* Wv = (const float*)d_in[5];
  const float* Wo = (const float*)d_in[6];
  float* out = (float*)d_out;
  char* ws = (char*)d_ws;

  unsigned short* qkv = (unsigned short*)(ws + 0);           // [4096][3072] bf16
  unsigned short* xb  = (unsigned short*)(ws + 25165824);    // [4096][2048] bf16; reused as attn-out
  unsigned short* wt  = (unsigned short*)(ws + 41943040);    // WqkvT; later WoT
  unsigned short* qb  = (unsigned short*)(ws + 54525952);    // roped q [4096][2048]
  unsigned short* kb  = (unsigned short*)(ws + 71303168);    // roped k [b][kvh][2048][64]
  unsigned short* vt  = (unsigned short*)(ws + 75497472);    // v^T [b][kvh][64][2048]

  dim3 tb(32, 8);
  convx_kernel<<<8192, 256, 0, stream>>>(x, xb, 2097152);
  transpose_conv_kernel<<<dim3(64, 64), tb, 0, stream>>>(Wq, wt, 2048, 2048);
  transpose_conv_kernel<<<dim3(16, 64), tb, 0, stream>>>(Wk, wt + (size_t)2048 * 2048, 2048, 512);
  transpose_conv_kernel<<<dim3(16, 64), tb, 0, stream>>>(Wv, wt + (size_t)2560 * 2048, 2048, 512);
  gemm4p_kernel<3, true><<<512, 256, 0, stream>>>(xb, wt, qkv, 4096, 3072, 2048, 16);
  rope_kernel<<<20480, 256, 0, stream>>>(qkv, cb, sb, qb, kb);
  vtrans_kernel<<<dim3(32, 16), 256, 0, stream>>>(qkv, vt);
  transpose_conv_kernel<<<dim3(64, 64), tb, 0, stream>>>(Wo, wt, 2048, 2048);  // wt now = WoT
  attn_kernel<<<1024, 256, 0, stream>>>(qb, kb, vt, xb);                       // xb now = attn features
  gemm4p_kernel<2, false><<<512, 256, 0, stream>>>(xb, wt, out, 4096, 2048, 2048, 16);
}

// Round 17
// 176.888 us; speedup vs baseline: 1.1078x; 1.0651x over previous
//
#include <hip/hip_runtime.h>
#include <hip/hip_bf16.h>

// Fused attention block: x@Wqkv -> RoPE -> causal GQA flash attention -> @Wo
// bf16 MFMA compute everywhere (2% abs tolerance), f32 I/O.

typedef __attribute__((ext_vector_type(8))) short short8;   // 8 bf16 = 4 VGPR (MFMA A/B frag)
typedef __attribute__((ext_vector_type(4))) float f32x4;    // 16x16 MFMA C/D frag
typedef __attribute__((ext_vector_type(16))) float f32x16;  // 32x32 MFMA C/D frag
typedef __attribute__((ext_vector_type(2))) int i32x2;
typedef __attribute__((ext_vector_type(4))) int i32x4;

__device__ __forceinline__ unsigned short f2bfu(float f){
  unsigned u = __float_as_uint(f);
  u += 0x7FFFu + ((u >> 16) & 1u);      // RNE (no NaNs in this workload)
  return (unsigned short)(u >> 16);
}
__device__ __forceinline__ float bfu2f(unsigned short u){
  return __uint_as_float(((unsigned)u) << 16);
}
// packed f32x2 -> bf16x2 (RNE), single VALU op
__device__ __forceinline__ unsigned cvt_pk_bf16(float lo, float hi){
  unsigned r;
  asm("v_cvt_pk_bf16_f32 %0, %1, %2" : "=v"(r) : "v"(lo), "v"(hi));
  return r;
}
// permlane32_swap: ret[0] = {a_lo, b_lo-of-partner}, ret[1] = {a_hi-of-partner, b_hi}
__device__ __forceinline__ i32x2 pl32swap(int a, int b){
  auto r = __builtin_amdgcn_permlane32_swap(a, b, false, false);
  return __builtin_bit_cast(i32x2, r);
}
// swizzled element offset in a 64-col bf16 row: slot = 16B unit 0..7, XOR row&7
__device__ __forceinline__ int swz64(int row, int slot){
  return row * 64 + (((slot) ^ (row & 7)) << 3);
}
template<int N> __device__ __forceinline__ void vm_wait(){
  if constexpr (N == 10)      asm volatile("s_waitcnt vmcnt(10)" ::: "memory");
  else if constexpr (N == 8)  asm volatile("s_waitcnt vmcnt(8)" ::: "memory");
  else if constexpr (N == 7)  asm volatile("s_waitcnt vmcnt(7)" ::: "memory");
  else if constexpr (N == 6)  asm volatile("s_waitcnt vmcnt(6)" ::: "memory");
  else if constexpr (N == 5)  asm volatile("s_waitcnt vmcnt(5)" ::: "memory");
  else if constexpr (N == 4)  asm volatile("s_waitcnt vmcnt(4)" ::: "memory");
  else if constexpr (N == 3)  asm volatile("s_waitcnt vmcnt(3)" ::: "memory");
  else if constexpr (N == 2)  asm volatile("s_waitcnt vmcnt(2)" ::: "memory");
  else                        asm volatile("s_waitcnt vmcnt(0)" ::: "memory");
}

// ---------------- elementwise f32 -> bf16 ----------------
__global__ void convx_kernel(const float* __restrict__ x, unsigned short* __restrict__ xb, int n4){
  int i = blockIdx.x * blockDim.x + threadIdx.x;
  if (i >= n4) return;
  float4 v = reinterpret_cast<const float4*>(x)[i];
  ushort4 o;
  o.x = f2bfu(v.x); o.y = f2bfu(v.y); o.z = f2bfu(v.z); o.w = f2bfu(v.w);
  reinterpret_cast<ushort4*>(xb)[i] = o;
}

// ------- all four W transposes in one launch: out[n][k] = (bf16)in[k][n] -------
// flattened tile ids: [0,4096) Wq -> wt, [4096,5120) Wk -> wt+2048*2048,
// [5120,6144) Wv -> wt+2560*2048, [6144,10240) Wo -> wot.  K = 2048 for all.
__global__ void wtrans_all_kernel(const float* __restrict__ Wq, const float* __restrict__ Wk,
                                  const float* __restrict__ Wv, const float* __restrict__ Wo,
                                  unsigned short* __restrict__ wt, unsigned short* __restrict__ wot){
  __shared__ float t[32][33];
  int tile = blockIdx.x;
  const float* in; unsigned short* out; int Nin, bx;
  if (tile < 4096)      { in = Wq; out = wt;                          Nin = 2048; bx = tile & 63;  tile >>= 6; }
  else if (tile < 5120) { in = Wk; out = wt + (size_t)2048 * 2048;    Nin = 512;  tile -= 4096; bx = tile & 15; tile >>= 4; }
  else if (tile < 6144) { in = Wv; out = wt + (size_t)2560 * 2048;    Nin = 512;  tile -= 5120; bx = tile & 15; tile >>= 4; }
  else                  { in = Wo; out = wot;                         Nin = 2048; tile -= 6144; bx = tile & 63; tile >>= 6; }
  const int c0 = bx * 32, r0 = tile * 32;   // r0 over K=2048, c0 over Nin
  int tx = threadIdx.x, ty = threadIdx.y;   // 32 x 8
  #pragma unroll
  for (int i = ty; i < 32; i += 8) t[i][tx] = in[(size_t)(r0 + i) * Nin + c0 + tx];
  __syncthreads();
  #pragma unroll
  for (int i = ty; i < 32; i += 8) out[(size_t)(c0 + i) * 2048 + r0 + tx] = f2bfu(t[tx][i]);
}

// ========= 128 x (NF*64) 4-phase bf16 GEMM, 2 blocks/CU: C = A[M][K] * B^T[N][K] =========
// (verified R15/R16; see comments there)
#define PH4(SLOT,KK,VMW,...) { \
  const unsigned short* sAc = &sA[SLOT][(KK)*4096]; \
  const unsigned short* sBc = &sB[SLOT][(KK)*RB]; \
  short8 afr[4]; short8 bfr[6]; \
  _Pragma("unroll") for (int m_ = 0; m_ < 4; m_++) \
    afr[m_] = *reinterpret_cast<const short8*>(sAc + aOff[m_]); \
  _Pragma("unroll") for (int n_ = 0; n_ < NFR; n_++) \
    bfr[n_] = *reinterpret_cast<const short8*>(sBc + bOff[n_]); \
  __VA_ARGS__; \
  __builtin_amdgcn_s_barrier(); \
  asm volatile("s_waitcnt lgkmcnt(0)" ::: "memory"); \
  __builtin_amdgcn_sched_barrier(0); \
  __builtin_amdgcn_s_setprio(1); \
  _Pragma("unroll") for (int m_ = 0; m_ < 4; m_++){ \
    _Pragma("unroll") for (int n_ = 0; n_ < NFR; n_++){ \
      acc[m_][n_] = __builtin_amdgcn_mfma_f32_16x16x32_bf16(afr[m_], bfr[n_], acc[m_][n_], 0, 0, 0); }} \
  __builtin_amdgcn_s_setprio(0); \
  VMW; \
  __builtin_amdgcn_s_barrier(); \
}

template<int NF, bool OUTBF16>
__global__ __launch_bounds__(256, 2) void gemm4p_kernel(const unsigned short* __restrict__ A,
                                                        const unsigned short* __restrict__ B,
                                                        void* __restrict__ Cp,
                                                        int M, int N, int K, int nbx){
  constexpr int NFR = 2 * NF;                 // n-frags per wave
  constexpr int RB  = NF * 2048;              // elems per B (slot,kk) region (NF*64 rows x 32)
  constexpr int VMS = 2 * (2 + NF);           // per-phase counted wait (2-phase issue window)
  __shared__ unsigned short sA[2][8192];      // 32 KiB  (slot = 2 kk x 128 rows x 32 elems)
  __shared__ unsigned short sB[2][2 * RB];    // NF=3: 48 KiB, NF=2: 32 KiB
  const int tid = threadIdx.x;
  const int l = tid & 63, w = tid >> 6;       // 4 waves
  const int quad = l >> 4, c16 = l & 15;
  // XCD-aware bijective grid swizzle (gridDim.x % 8 == 0)
  const int cpx = (int)gridDim.x >> 3;
  const int id2 = ((int)blockIdx.x & 7) * cpx + ((int)blockIdx.x >> 3);
  const int bx = id2 % nbx, by = id2 / nbx;
  const int row0 = by * 128, col0 = bx * (NF * 64);
  const int wr = w >> 1, wc = w & 1;

  // staging source pointers (pre-swizzled column unit); per-wave: A 2 instr, B NF instr
  const unsigned short* gAp[2];
  const unsigned short* gBp[NF];
  #pragma unroll
  for (int j = 0; j < 2; j++){
    int rl = w * 32 + j * 16 + (l >> 2);
    gAp[j] = A + (size_t)(row0 + rl) * K + ((((l & 3) ^ ((rl >> 1) & 3))) << 3);
  }
  #pragma unroll
  for (int j = 0; j < NF; j++){
    int rl = w * (16 * NF) + j * 16 + (l >> 2);
    gBp[j] = B + (size_t)(col0 + rl) * K + ((((l & 3) ^ ((rl >> 1) & 3))) << 3);
  }

  auto stA = [&](int slot, int kk, int col){
    #pragma unroll
    for (int j = 0; j < 2; j++)
      __builtin_amdgcn_global_load_lds((const __attribute__((address_space(1))) void*)(gAp[j] + col),
          (__attribute__((address_space(3))) void*)(&sA[slot][kk * 4096 + w * 1024 + j * 512]), 16, 0, 0);
  };
  auto stB = [&](int slot, int kk, int col){
    #pragma unroll
    for (int j = 0; j < NF; j++)
      __builtin_amdgcn_global_load_lds((const __attribute__((address_space(1))) void*)(gBp[j] + col),
          (__attribute__((address_space(3))) void*)(&sB[slot][kk * RB + w * (512 * NF) + j * 512]), 16, 0, 0);
  };

  // reader fragment offsets (within a [row][32] k-half region)
  int aOff[4], bOff[6];
  #pragma unroll
  for (int mf = 0; mf < 4; mf++){
    int row = wr * 64 + mf * 16 + c16;
    aOff[mf] = row * 32 + ((quad ^ ((row >> 1) & 3)) << 3);
  }
  #pragma unroll
  for (int nf = 0; nf < NFR; nf++){
    int row = wc * (NF * 32) + nf * 16 + c16;
    bOff[nf] = row * 32 + ((quad ^ ((row >> 1) & 3)) << 3);
  }

  // prologue: regions (0,0),(0,1),(1,0); vmcnt leaves the last 2 regions in flight
  stA(0, 0, 0);  stB(0, 0, 0);
  stA(0, 1, 32); stB(0, 1, 32);
  stA(1, 0, 64); stB(1, 0, 64);
  vm_wait<VMS>();
  __builtin_amdgcn_s_barrier();

  f32x4 acc[4][6] = {};
  const int NI = K >> 7;   // iterations of 2 K-tiles (BK=64)
  #pragma unroll 1
  for (int j = 0; j < NI - 1; ++j){
    const int t1c  = (2 * j + 1) * 64 + 32;  // tile 2j+1, k1
    const int t2c0 = (2 * j + 2) * 64;       // tile 2j+2, k0
    const int t2c1 = t2c0 + 32;
    const int t3c0 = (2 * j + 3) * 64;       // tile 2j+3, k0
    PH4(0,0, vm_wait<VMS>(), stA(1,1,t1c);  stB(1,1,t1c))
    PH4(0,1, vm_wait<VMS>(), stA(0,0,t2c0); stB(0,0,t2c0))
    PH4(1,0, vm_wait<VMS>(), stA(0,1,t2c1); stB(0,1,t2c1))
    PH4(1,1, vm_wait<VMS>(), stA(1,0,t3c0); stB(1,0,t3c0))
  }
  { // peeled last iteration: only the last tile's k1 remains to stage
    const int t1c = K - 32;
    PH4(0,0, vm_wait<VMS>(), stA(1,1,t1c); stB(1,1,t1c))
    PH4(0,1, vm_wait<0>(), ;)
    PH4(1,0, vm_wait<0>(), ;)
    PH4(1,1, (void)0, ;)
  }

  // epilogue
  #pragma unroll
  for (int mf = 0; mf < 4; mf++)
    #pragma unroll
    for (int nf = 0; nf < NFR; nf++)
      #pragma unroll
      for (int r = 0; r < 4; r++){
        size_t off = (size_t)(row0 + wr * 64 + mf * 16 + quad * 4 + r) * N + (col0 + wc * (NF * 32) + nf * 16 + c16);
        if (OUTBF16) ((unsigned short*)Cp)[off] = f2bfu(acc[mf][nf][r]);
        else         ((float*)Cp)[off] = acc[mf][nf][r];
      }
}

// -------- prep_kv: K-rope (qkv cols [2048,2560) -> kb) + V transpose (cols [2560,3072) -> vt) --------
// blocks [0,4096): k-rope, 256 pairs each; blocks [4096,4608): vtrans 64x64 tiles.
__global__ void prep_kv_kernel(const unsigned short* __restrict__ qkv, const float* __restrict__ cosb,
                               const float* __restrict__ sinb, unsigned short* __restrict__ Ko,
                               unsigned short* __restrict__ Vt){
  __shared__ float t[64][65];
  const int blk = blockIdx.x;
  const int tid = threadIdx.x;
  if (blk < 4096){
    int j = blk * 256 + tid;
    int m = j >> 8, p = j & 255;
    int kvh = p >> 5, i = p & 31;
    int s = m & 2047, b = m >> 11;
    unsigned pr = *reinterpret_cast<const unsigned*>(qkv + (size_t)m * 3072 + 2048 + kvh * 64 + 2 * i);
    float t0 = bfu2f((unsigned short)(pr & 0xFFFFu));
    float t1 = bfu2f((unsigned short)(pr >> 16));
    float c = cosb[s * 32 + i], sn = sinb[s * 32 + i];
    float o0 = t0 * c - t1 * sn;
    float o1 = t0 * sn + t1 * c;
    unsigned ow = (unsigned)f2bfu(o0) | ((unsigned)f2bfu(o1) << 16);
    *reinterpret_cast<unsigned*>(Ko + ((size_t)(b * 8 + kvh) * 2048 + s) * 64 + 2 * i) = ow;
  } else {
    const int bid2 = blk - 4096;
    const int s0 = (bid2 & 31) * 64, bh = bid2 >> 5;
    const int b = bh >> 3, kvh = bh & 7;
    #pragma unroll
    for (int it = 0; it < 16; it++){
      int id = it * 256 + tid;
      int sl = id >> 6, d = id & 63;
      t[sl][d] = bfu2f(qkv[(size_t)(b * 2048 + s0 + sl) * 3072 + 2560 + kvh * 64 + d]);
    }
    __syncthreads();
    #pragma unroll
    for (int it = 0; it < 16; it++){
      int id = it * 256 + tid;
      int dl = id >> 6, sl = id & 63;
      Vt[((size_t)(b * 8 + kvh) * 64 + dl) * 2048 + s0 + sl] = f2bfu(t[sl][dl]);
    }
  }
}

// ---------------- causal GQA flash attention (32x32 swapped, in-register P, no-max) ----------------
// (verified R13/R16) + fused Q-RoPE: reads raw q columns of qkv directly (qb buffer deleted);
// rope applied in-register at block start (pairs adjacent in frag; cos/sin via 2x4 float4,
// L2-resident; ~100 VALU amortized over nt tiles). __launch_bounds__(256,4) for residency.
__global__ __launch_bounds__(256, 4) void attn_kernel(const unsigned short* __restrict__ qkv,
                                                      const float* __restrict__ cosb,
                                                      const float* __restrict__ sinb,
                                                      const unsigned short* __restrict__ Kt,
                                                      const unsigned short* __restrict__ Vt,
                                                      unsigned short* __restrict__ O){
  __shared__ unsigned short sK[2][64 * 64];
  __shared__ unsigned short sV[2][64 * 64];
  const int tid = threadIdx.x;
  const int l = tid & 63, w = tid >> 6;
  const int q32 = l & 31, hi = l >> 5;
  const int bid = blockIdx.x;
  const int qt = 15 - (bid >> 6);         // largest kv-trip blocks dispatch first (LPT)
  const int bh = bid & 63;
  const int b = bh >> 5, h = bh & 31, kvh = h >> 2;
  const int q0w = qt * 128 + w * 32;
  const int nt = 2 * qt + 2;              // uniform across the block's 4 waves

  const unsigned short* Kb = Kt + (size_t)(b * 8 + kvh) * 2048 * 64;
  const unsigned short* Vb = Vt + (size_t)(b * 8 + kvh) * 64 * 2048;

  auto stage = [&](int kv0, int buf){
    #pragma unroll
    for (int c = 0; c < 2; c++){
      const int rl = w * 16 + c * 8 + (l >> 3);
      const int ce = (((l & 7) ^ (l >> 3)) << 3);
      __builtin_amdgcn_global_load_lds(
        (const __attribute__((address_space(1))) void*)(Kb + (size_t)(kv0 + rl) * 64 + ce),
        (__attribute__((address_space(3))) void*)(&sK[buf][(w * 16 + c * 8) * 64]), 16, 0, 0);
      __builtin_amdgcn_global_load_lds(
        (const __attribute__((address_space(1))) void*)(Vb + (size_t)rl * 2048 + kv0 + ce),
        (__attribute__((address_space(3))) void*)(&sV[buf][(w * 16 + c * 8) * 64]), 16, 0, 0);
    }
  };

  // Q B-frags with fused RoPE: lane holds Q[q = q0w+q32][kd*16 + hi*8 + e], rope pairs
  // (2i, 2i+1) are adjacent elements; i = kd*8 + hi*4 + j for pair j in frag kd.
  short8 qv[4];
  {
    const int s = q0w + q32;
    const unsigned short* Qp = qkv + (size_t)(b * 2048 + s) * 3072 + h * 64 + hi * 8;
    const float* cp = cosb + s * 32 + hi * 4;
    const float* sp = sinb + s * 32 + hi * 4;
    const float SC = 0.18033688011112042f;   // (1/8) * log2(e): exp2-domain softmax scale
    #pragma unroll
    for (int kd = 0; kd < 4; kd++){
      short8 raw = *reinterpret_cast<const short8*>(Qp + kd * 16);
      float4 c4 = *reinterpret_cast<const float4*>(cp + kd * 8);
      float4 s4 = *reinterpret_cast<const float4*>(sp + kd * 8);
      unsigned pk[4];
      #pragma unroll
      for (int j = 0; j < 4; j++){
        float t0 = bfu2f((unsigned short)raw[2 * j]);
        float t1 = bfu2f((unsigned short)raw[2 * j + 1]);
        float cc = (&c4.x)[j], sn = (&s4.x)[j];
        pk[j] = cvt_pk_bf16((t0 * cc - t1 * sn) * SC, (t0 * sn + t1 * cc) * SC);
      }
      i32x4 q_ = {(int)pk[0], (int)pk[1], (int)pk[2], (int)pk[3]};
      qv[kd] = __builtin_bit_cast(short8, q_);
    }
  }

  const short8 ones = {0x3F80, 0x3F80, 0x3F80, 0x3F80, 0x3F80, 0x3F80, 0x3F80, 0x3F80};

  f32x16 accA = {}, accB = {};   // O cols d = dh*32 + q32; rows q via reg map
  f32x16 accl = {};              // denominator (all cols identical)

  // build one PV A-frag (k-halfslice of 16) from 8 z-regs starting at R0
#define MKAP(Z, R0, AP) { \
    unsigned A_ = cvt_pk_bf16(Z[R0+0], Z[R0+1]); \
    unsigned B_ = cvt_pk_bf16(Z[R0+2], Z[R0+3]); \
    unsigned C_ = cvt_pk_bf16(Z[R0+4], Z[R0+5]); \
    unsigned D_ = cvt_pk_bf16(Z[R0+6], Z[R0+7]); \
    i32x2 s1_ = pl32swap((int)A_, (int)C_); \
    i32x2 s2_ = pl32swap((int)B_, (int)D_); \
    i32x4 q_ = {s1_[0], s2_[0], s1_[1], s2_[1]}; \
    AP = __builtin_bit_cast(short8, q_); \
  }

  stage(0, 0);
  vm_wait<0>();
  __builtin_amdgcn_s_barrier();

  for (int t = 0; t < nt; ++t){
    const int kv0 = t * 64;
    const int buf = t & 1;
    if (t + 1 < nt) stage((t + 1) * 64, buf ^ 1);   // prefetch stays in flight over compute

    const unsigned short* sKc = &sK[buf][0];
    const unsigned short* sVc = &sV[buf][0];

    // ---- S^T = K Q^T (two 32x32 tiles: k 0-31, 32-63) ----
    f32x16 z0 = {}, z1 = {};
    __builtin_amdgcn_s_setprio(1);
    #pragma unroll
    for (int kd = 0; kd < 4; kd++){
      const int u = kd * 2 + hi;
      short8 ak0 = *reinterpret_cast<const short8*>(&sKc[swz64(q32, u)]);
      short8 ak1 = *reinterpret_cast<const short8*>(&sKc[swz64(32 + q32, u)]);
      z0 = __builtin_amdgcn_mfma_f32_32x32x16_bf16(ak0, qv[kd], z0, 0, 0, 0);
      z1 = __builtin_amdgcn_mfma_f32_32x32x16_bf16(ak1, qv[kd], z1, 0, 0, 0);
    }
    __builtin_amdgcn_s_setprio(0);

    // ---- causal mask (wave-uniform branch; near-diagonal + fully-masked tiles) ----
    if (kv0 + 63 > q0w){
      const int qg = q0w + q32;
      #pragma unroll
      for (int r = 0; r < 16; r++){
        const int kr = (r & 3) + 8 * (r >> 2) + 4 * hi;
        if (kv0 + kr > qg)      z0[r] = -1e30f;
        if (kv0 + 32 + kr > qg) z1[r] = -1e30f;
      }
    }

    // ---- P = exp2(S) directly (no max subtraction; lane-local row; masked -> 0) ----
    #pragma unroll
    for (int r = 0; r < 16; r++){
      z0[r] = __builtin_amdgcn_exp2f(z0[r]);
      z1[r] = __builtin_amdgcn_exp2f(z1[r]);
    }

    // ---- PV + ones-denominator, per k-tile (in-register P via cvt_pk + permlane) ----
    short8 apA, apB;
    __builtin_amdgcn_s_setprio(1);
    // kt = 0: k-slices 0,1
    MKAP(z0, 0, apA)
    MKAP(z0, 8, apB)
    accl = __builtin_amdgcn_mfma_f32_32x32x16_bf16(apA, ones, accl, 0, 0, 0);
    accl = __builtin_amdgcn_mfma_f32_32x32x16_bf16(apB, ones, accl, 0, 0, 0);
    {
      short8 bv;
      bv = *reinterpret_cast<const short8*>(&sVc[swz64(q32, 0 * 2 + hi)]);
      accA = __builtin_amdgcn_mfma_f32_32x32x16_bf16(apA, bv, accA, 0, 0, 0);
      bv = *reinterpret_cast<const short8*>(&sVc[swz64(q32, 1 * 2 + hi)]);
      accA = __builtin_amdgcn_mfma_f32_32x32x16_bf16(apB, bv, accA, 0, 0, 0);
      bv = *reinterpret_cast<const short8*>(&sVc[swz64(32 + q32, 0 * 2 + hi)]);
      accB = __builtin_amdgcn_mfma_f32_32x32x16_bf16(apA, bv, accB, 0, 0, 0);
      bv = *reinterpret_cast<const short8*>(&sVc[swz64(32 + q32, 1 * 2 + hi)]);
      accB = __builtin_amdgcn_mfma_f32_32x32x16_bf16(apB, bv, accB, 0, 0, 0);
    }
    // kt = 1: k-slices 2,3
    MKAP(z1, 0, apA)
    MKAP(z1, 8, apB)
    accl = __builtin_amdgcn_mfma_f32_32x32x16_bf16(apA, ones, accl, 0, 0, 0);
    accl = __builtin_amdgcn_mfma_f32_32x32x16_bf16(apB, ones, accl, 0, 0, 0);
    {
      short8 bv;
      bv = *reinterpret_cast<const short8*>(&sVc[swz64(q32, 2 * 2 + hi)]);
      accA = __builtin_amdgcn_mfma_f32_32x32x16_bf16(apA, bv, accA, 0, 0, 0);
      bv = *reinterpret_cast<const short8*>(&sVc[swz64(q32, 3 * 2 + hi)]);
      accA = __builtin_amdgcn_mfma_f32_32x32x16_bf16(apB, bv, accA, 0, 0, 0);
      bv = *reinterpret_cast<const short8*>(&sVc[swz64(32 + q32, 2 * 2 + hi)]);
      accB = __builtin_amdgcn_mfma_f32_32x32x16_bf16(apA, bv, accB, 0, 0, 0);
      bv = *reinterpret_cast<const short8*>(&sVc[swz64(32 + q32, 3 * 2 + hi)]);
      accB = __builtin_amdgcn_mfma_f32_32x32x16_bf16(apB, bv, accB, 0, 0, 0);
    }
    __builtin_amdgcn_s_setprio(0);

    vm_wait<0>();
    __builtin_amdgcn_s_barrier();
  }
#undef MKAP

  // ---- epilogue: normalize rows (accl rows align with acc rows) and store ----
  #pragma unroll
  for (int r = 0; r < 16; r++){
    const float inv = 1.0f / accl[r];
    const int qrow = q0w + (r & 3) + 8 * (r >> 2) + 4 * hi;
    const size_t base = (size_t)(b * 2048 + qrow) * 2048 + h * 64 + q32;
    O[base]      = f2bfu(accA[r] * inv);
    O[base + 32] = f2bfu(accB[r] * inv);
  }
}

extern "C" void kernel_launch(void* const* d_in, const int* in_sizes, int n_in,
                              void* d_out, int out_size, void* d_ws, size_t ws_size,
                              hipStream_t stream){
  (void)in_sizes; (void)n_in; (void)out_size; (void)ws_size;
  const float* x  = (const float*)d_in[0];
  const float* cb = (const float*)d_in[1];
  const float* sb = (const float*)d_in[2];
  const float* Wq = (const float*)d_in[3];
  const float* Wk = (const float*)d_in[4];
  const float* Wv = (const float*)d_in[5];
  const float* Wo = (const float*)d_in[6];
  float* out = (float*)d_out;
  char* ws = (char*)d_ws;

  unsigned short* qkv = (unsigned short*)(ws + 0);           // [4096][3072] bf16
  unsigned short* xb  = (unsigned short*)(ws + 25165824);    // [4096][2048] bf16; reused as attn-out
  unsigned short* wt  = (unsigned short*)(ws + 41943040);    // WqkvT [3072][2048]
  unsigned short* wot = (unsigned short*)(ws + 54525952);    // WoT [2048][2048] (qb's old slot)
  unsigned short* kb  = (unsigned short*)(ws + 71303168);    // roped k [b][kvh][2048][64]
  unsigned short* vt  = (unsigned short*)(ws + 75497472);    // v^T [b][kvh][64][2048]

  dim3 tb(32, 8);
  convx_kernel<<<8192, 256, 0, stream>>>(x, xb, 2097152);
  wtrans_all_kernel<<<10240, tb, 0, stream>>>(Wq, Wk, Wv, Wo, wt, wot);
  gemm4p_kernel<3, true><<<512, 256, 0, stream>>>(xb, wt, qkv, 4096, 3072, 2048, 16);
  prep_kv_kernel<<<4608, 256, 0, stream>>>(qkv, cb, sb, kb, vt);
  attn_kernel<<<1024, 256, 0, stream>>>(qkv, cb, sb, kb, vt, xb);   // xb now = attn features
  gemm4p_kernel<2, false><<<512, 256, 0, stream>>>(xb, wot, out, 4096, 2048, 2048, 16);
}

// Round 18
// 175.106 us; speedup vs baseline: 1.1190x; 1.0102x over previous
//
#include <hip/hip_runtime.h>
#include <hip/hip_bf16.h>

// Fused attention block: x@Wqkv -> RoPE -> causal GQA flash attention -> @Wo
// bf16 MFMA compute everywhere (2% abs tolerance), f32 I/O.

typedef __attribute__((ext_vector_type(8))) short short8;   // 8 bf16 = 4 VGPR (MFMA A/B frag)
typedef __attribute__((ext_vector_type(4))) float f32x4;    // 16x16 MFMA C/D frag
typedef __attribute__((ext_vector_type(16))) float f32x16;  // 32x32 MFMA C/D frag
typedef __attribute__((ext_vector_type(2))) int i32x2;
typedef __attribute__((ext_vector_type(4))) int i32x4;

__device__ __forceinline__ unsigned short f2bfu(float f){
  unsigned u = __float_as_uint(f);
  u += 0x7FFFu + ((u >> 16) & 1u);      // RNE (no NaNs in this workload)
  return (unsigned short)(u >> 16);
}
__device__ __forceinline__ float bfu2f(unsigned short u){
  return __uint_as_float(((unsigned)u) << 16);
}
// packed f32x2 -> bf16x2 (RNE), single VALU op
__device__ __forceinline__ unsigned cvt_pk_bf16(float lo, float hi){
  unsigned r;
  asm("v_cvt_pk_bf16_f32 %0, %1, %2" : "=v"(r) : "v"(lo), "v"(hi));
  return r;
}
// permlane32_swap: ret[0] = {a_lo, b_lo-of-partner}, ret[1] = {a_hi-of-partner, b_hi}
__device__ __forceinline__ i32x2 pl32swap(int a, int b){
  auto r = __builtin_amdgcn_permlane32_swap(a, b, false, false);
  return __builtin_bit_cast(i32x2, r);
}
// swizzled element offset in a 64-col bf16 row: slot = 16B unit 0..7, XOR row&7
__device__ __forceinline__ int swz64(int row, int slot){
  return row * 64 + (((slot) ^ (row & 7)) << 3);
}
template<int N> __device__ __forceinline__ void vm_wait(){
  if constexpr (N == 10)      asm volatile("s_waitcnt vmcnt(10)" ::: "memory");
  else if constexpr (N == 8)  asm volatile("s_waitcnt vmcnt(8)" ::: "memory");
  else if constexpr (N == 7)  asm volatile("s_waitcnt vmcnt(7)" ::: "memory");
  else if constexpr (N == 6)  asm volatile("s_waitcnt vmcnt(6)" ::: "memory");
  else if constexpr (N == 5)  asm volatile("s_waitcnt vmcnt(5)" ::: "memory");
  else if constexpr (N == 4)  asm volatile("s_waitcnt vmcnt(4)" ::: "memory");
  else if constexpr (N == 3)  asm volatile("s_waitcnt vmcnt(3)" ::: "memory");
  else if constexpr (N == 2)  asm volatile("s_waitcnt vmcnt(2)" ::: "memory");
  else                        asm volatile("s_waitcnt vmcnt(0)" ::: "memory");
}

// ------- merged input prep: x -> bf16 AND all four W transposes, one launch -------
// blocks [0,8192): convx (256 float4 each); [8192,18432): W-transpose 32x32 tiles
// (ids: [0,4096) Wq -> wt, [4096,5120) Wk, [5120,6144) Wv, [6144,10240) Wo -> wot).
__global__ void prep_in_kernel(const float* __restrict__ x, unsigned short* __restrict__ xb,
                               const float* __restrict__ Wq, const float* __restrict__ Wk,
                               const float* __restrict__ Wv, const float* __restrict__ Wo,
                               unsigned short* __restrict__ wt, unsigned short* __restrict__ wot){
  __shared__ float t[32][33];
  const int blk = blockIdx.x;
  const int tid = threadIdx.x;
  if (blk < 8192){
    int i = blk * 256 + tid;
    float4 v = reinterpret_cast<const float4*>(x)[i];
    ushort4 o;
    o.x = f2bfu(v.x); o.y = f2bfu(v.y); o.z = f2bfu(v.z); o.w = f2bfu(v.w);
    reinterpret_cast<ushort4*>(xb)[i] = o;
  } else {
    int tile = blk - 8192;
    const float* in; unsigned short* out; int Nin, bx;
    if (tile < 4096)      { in = Wq; out = wt;                       Nin = 2048; bx = tile & 63;  tile >>= 6; }
    else if (tile < 5120) { in = Wk; out = wt + (size_t)2048 * 2048; Nin = 512;  tile -= 4096; bx = tile & 15; tile >>= 4; }
    else if (tile < 6144) { in = Wv; out = wt + (size_t)2560 * 2048; Nin = 512;  tile -= 5120; bx = tile & 15; tile >>= 4; }
    else                  { in = Wo; out = wot;                      Nin = 2048; tile -= 6144; bx = tile & 63; tile >>= 6; }
    const int c0 = bx * 32, r0 = tile * 32;   // r0 over K=2048, c0 over Nin
    const int tx = tid & 31, ty = tid >> 5;   // 32 x 8
    #pragma unroll
    for (int i = ty; i < 32; i += 8) t[i][tx] = in[(size_t)(r0 + i) * Nin + c0 + tx];
    __syncthreads();
    #pragma unroll
    for (int i = ty; i < 32; i += 8) out[(size_t)(c0 + i) * 2048 + r0 + tx] = f2bfu(t[tx][i]);
  }
}

// ========= 128 x (NF*64) 4-phase bf16 GEMM, 2 blocks/CU: C = A[M][K] * B^T[N][K] =========
// (verified R15/R16; see comments there)
#define PH4(SLOT,KK,VMW,...) { \
  const unsigned short* sAc = &sA[SLOT][(KK)*4096]; \
  const unsigned short* sBc = &sB[SLOT][(KK)*RB]; \
  short8 afr[4]; short8 bfr[6]; \
  _Pragma("unroll") for (int m_ = 0; m_ < 4; m_++) \
    afr[m_] = *reinterpret_cast<const short8*>(sAc + aOff[m_]); \
  _Pragma("unroll") for (int n_ = 0; n_ < NFR; n_++) \
    bfr[n_] = *reinterpret_cast<const short8*>(sBc + bOff[n_]); \
  __VA_ARGS__; \
  __builtin_amdgcn_s_barrier(); \
  asm volatile("s_waitcnt lgkmcnt(0)" ::: "memory"); \
  __builtin_amdgcn_sched_barrier(0); \
  __builtin_amdgcn_s_setprio(1); \
  _Pragma("unroll") for (int m_ = 0; m_ < 4; m_++){ \
    _Pragma("unroll") for (int n_ = 0; n_ < NFR; n_++){ \
      acc[m_][n_] = __builtin_amdgcn_mfma_f32_16x16x32_bf16(afr[m_], bfr[n_], acc[m_][n_], 0, 0, 0); }} \
  __builtin_amdgcn_s_setprio(0); \
  VMW; \
  __builtin_amdgcn_s_barrier(); \
}

template<int NF, bool OUTBF16>
__global__ __launch_bounds__(256, 2) void gemm4p_kernel(const unsigned short* __restrict__ A,
                                                        const unsigned short* __restrict__ B,
                                                        void* __restrict__ Cp,
                                                        int M, int N, int K, int nbx){
  constexpr int NFR = 2 * NF;                 // n-frags per wave
  constexpr int RB  = NF * 2048;              // elems per B (slot,kk) region (NF*64 rows x 32)
  constexpr int VMS = 2 * (2 + NF);           // per-phase counted wait (2-phase issue window)
  __shared__ unsigned short sA[2][8192];      // 32 KiB  (slot = 2 kk x 128 rows x 32 elems)
  __shared__ unsigned short sB[2][2 * RB];    // NF=3: 48 KiB, NF=2: 32 KiB
  const int tid = threadIdx.x;
  const int l = tid & 63, w = tid >> 6;       // 4 waves
  const int quad = l >> 4, c16 = l & 15;
  // XCD-aware bijective grid swizzle (gridDim.x % 8 == 0)
  const int cpx = (int)gridDim.x >> 3;
  const int id2 = ((int)blockIdx.x & 7) * cpx + ((int)blockIdx.x >> 3);
  const int bx = id2 % nbx, by = id2 / nbx;
  const int row0 = by * 128, col0 = bx * (NF * 64);
  const int wr = w >> 1, wc = w & 1;

  // staging source pointers (pre-swizzled column unit); per-wave: A 2 instr, B NF instr
  const unsigned short* gAp[2];
  const unsigned short* gBp[NF];
  #pragma unroll
  for (int j = 0; j < 2; j++){
    int rl = w * 32 + j * 16 + (l >> 2);
    gAp[j] = A + (size_t)(row0 + rl) * K + ((((l & 3) ^ ((rl >> 1) & 3))) << 3);
  }
  #pragma unroll
  for (int j = 0; j < NF; j++){
    int rl = w * (16 * NF) + j * 16 + (l >> 2);
    gBp[j] = B + (size_t)(col0 + rl) * K + ((((l & 3) ^ ((rl >> 1) & 3))) << 3);
  }

  auto stA = [&](int slot, int kk, int col){
    #pragma unroll
    for (int j = 0; j < 2; j++)
      __builtin_amdgcn_global_load_lds((const __attribute__((address_space(1))) void*)(gAp[j] + col),
          (__attribute__((address_space(3))) void*)(&sA[slot][kk * 4096 + w * 1024 + j * 512]), 16, 0, 0);
  };
  auto stB = [&](int slot, int kk, int col){
    #pragma unroll
    for (int j = 0; j < NF; j++)
      __builtin_amdgcn_global_load_lds((const __attribute__((address_space(1))) void*)(gBp[j] + col),
          (__attribute__((address_space(3))) void*)(&sB[slot][kk * RB + w * (512 * NF) + j * 512]), 16, 0, 0);
  };

  // reader fragment offsets (within a [row][32] k-half region)
  int aOff[4], bOff[6];
  #pragma unroll
  for (int mf = 0; mf < 4; mf++){
    int row = wr * 64 + mf * 16 + c16;
    aOff[mf] = row * 32 + ((quad ^ ((row >> 1) & 3)) << 3);
  }
  #pragma unroll
  for (int nf = 0; nf < NFR; nf++){
    int row = wc * (NF * 32) + nf * 16 + c16;
    bOff[nf] = row * 32 + ((quad ^ ((row >> 1) & 3)) << 3);
  }

  // prologue: regions (0,0),(0,1),(1,0); vmcnt leaves the last 2 regions in flight
  stA(0, 0, 0);  stB(0, 0, 0);
  stA(0, 1, 32); stB(0, 1, 32);
  stA(1, 0, 64); stB(1, 0, 64);
  vm_wait<VMS>();
  __builtin_amdgcn_s_barrier();

  f32x4 acc[4][6] = {};
  const int NI = K >> 7;   // iterations of 2 K-tiles (BK=64)
  #pragma unroll 1
  for (int j = 0; j < NI - 1; ++j){
    const int t1c  = (2 * j + 1) * 64 + 32;  // tile 2j+1, k1
    const int t2c0 = (2 * j + 2) * 64;       // tile 2j+2, k0
    const int t2c1 = t2c0 + 32;
    const int t3c0 = (2 * j + 3) * 64;       // tile 2j+3, k0
    PH4(0,0, vm_wait<VMS>(), stA(1,1,t1c);  stB(1,1,t1c))
    PH4(0,1, vm_wait<VMS>(), stA(0,0,t2c0); stB(0,0,t2c0))
    PH4(1,0, vm_wait<VMS>(), stA(0,1,t2c1); stB(0,1,t2c1))
    PH4(1,1, vm_wait<VMS>(), stA(1,0,t3c0); stB(1,0,t3c0))
  }
  { // peeled last iteration: only the last tile's k1 remains to stage
    const int t1c = K - 32;
    PH4(0,0, vm_wait<VMS>(), stA(1,1,t1c); stB(1,1,t1c))
    PH4(0,1, vm_wait<0>(), ;)
    PH4(1,0, vm_wait<0>(), ;)
    PH4(1,1, (void)0, ;)
  }

  // epilogue
  #pragma unroll
  for (int mf = 0; mf < 4; mf++)
    #pragma unroll
    for (int nf = 0; nf < NFR; nf++)
      #pragma unroll
      for (int r = 0; r < 4; r++){
        size_t off = (size_t)(row0 + wr * 64 + mf * 16 + quad * 4 + r) * N + (col0 + wc * (NF * 32) + nf * 16 + c16);
        if (OUTBF16) ((unsigned short*)Cp)[off] = f2bfu(acc[mf][nf][r]);
        else         ((float*)Cp)[off] = acc[mf][nf][r];
      }
}

// -------- prep_kv: K-rope (qkv cols [2048,2560) -> kb) + V transpose (cols [2560,3072) -> vt) --------
__global__ void prep_kv_kernel(const unsigned short* __restrict__ qkv, const float* __restrict__ cosb,
                               const float* __restrict__ sinb, unsigned short* __restrict__ Ko,
                               unsigned short* __restrict__ Vt){
  __shared__ float t[64][65];
  const int blk = blockIdx.x;
  const int tid = threadIdx.x;
  if (blk < 4096){
    int j = blk * 256 + tid;
    int m = j >> 8, p = j & 255;
    int kvh = p >> 5, i = p & 31;
    int s = m & 2047, b = m >> 11;
    unsigned pr = *reinterpret_cast<const unsigned*>(qkv + (size_t)m * 3072 + 2048 + kvh * 64 + 2 * i);
    float t0 = bfu2f((unsigned short)(pr & 0xFFFFu));
    float t1 = bfu2f((unsigned short)(pr >> 16));
    float c = cosb[s * 32 + i], sn = sinb[s * 32 + i];
    float o0 = t0 * c - t1 * sn;
    float o1 = t0 * sn + t1 * c;
    unsigned ow = (unsigned)f2bfu(o0) | ((unsigned)f2bfu(o1) << 16);
    *reinterpret_cast<unsigned*>(Ko + ((size_t)(b * 8 + kvh) * 2048 + s) * 64 + 2 * i) = ow;
  } else {
    const int bid2 = blk - 4096;
    const int s0 = (bid2 & 31) * 64, bh = bid2 >> 5;
    const int b = bh >> 3, kvh = bh & 7;
    #pragma unroll
    for (int it = 0; it < 16; it++){
      int id = it * 256 + tid;
      int sl = id >> 6, d = id & 63;
      t[sl][d] = bfu2f(qkv[(size_t)(b * 2048 + s0 + sl) * 3072 + 2560 + kvh * 64 + d]);
    }
    __syncthreads();
    #pragma unroll
    for (int it = 0; it < 16; it++){
      int id = it * 256 + tid;
      int dl = id >> 6, sl = id & 63;
      Vt[((size_t)(b * 8 + kvh) * 64 + dl) * 2048 + s0 + sl] = f2bfu(t[sl][dl]);
    }
  }
}

// ---------------- causal GQA flash attention (32x32 swapped, in-register P, no-max) ----------------
// (verified R13/R16/R17: fused Q-RoPE, launch_bounds(256,4)) + fully-masked-tile skip:
// wave w's rows end at q0w+31; if kv0 > q0w+31 the whole tile is masked (P = 0, contributes
// nothing to acc/accl) -> skip QK^T/exp2/PV for that wave while keeping the staging/barrier
// protocol (waves 0,1 of every block save one wasted tile).
__global__ __launch_bounds__(256, 4) void attn_kernel(const unsigned short* __restrict__ qkv,
                                                      const float* __restrict__ cosb,
                                                      const float* __restrict__ sinb,
                                                      const unsigned short* __restrict__ Kt,
                                                      const unsigned short* __restrict__ Vt,
                                                      unsigned short* __restrict__ O){
  __shared__ unsigned short sK[2][64 * 64];
  __shared__ unsigned short sV[2][64 * 64];
  const int tid = threadIdx.x;
  const int l = tid & 63, w = tid >> 6;
  const int q32 = l & 31, hi = l >> 5;
  const int bid = blockIdx.x;
  const int qt = 15 - (bid >> 6);         // largest kv-trip blocks dispatch first (LPT)
  const int bh = bid & 63;
  const int b = bh >> 5, h = bh & 31, kvh = h >> 2;
  const int q0w = qt * 128 + w * 32;
  const int nt = 2 * qt + 2;              // uniform across the block's 4 waves

  const unsigned short* Kb = Kt + (size_t)(b * 8 + kvh) * 2048 * 64;
  const unsigned short* Vb = Vt + (size_t)(b * 8 + kvh) * 64 * 2048;

  auto stage = [&](int kv0, int buf){
    #pragma unroll
    for (int c = 0; c < 2; c++){
      const int rl = w * 16 + c * 8 + (l >> 3);
      const int ce = (((l & 7) ^ (l >> 3)) << 3);
      __builtin_amdgcn_global_load_lds(
        (const __attribute__((address_space(1))) void*)(Kb + (size_t)(kv0 + rl) * 64 + ce),
        (__attribute__((address_space(3))) void*)(&sK[buf][(w * 16 + c * 8) * 64]), 16, 0, 0);
      __builtin_amdgcn_global_load_lds(
        (const __attribute__((address_space(1))) void*)(Vb + (size_t)rl * 2048 + kv0 + ce),
        (__attribute__((address_space(3))) void*)(&sV[buf][(w * 16 + c * 8) * 64]), 16, 0, 0);
    }
  };

  // Q B-frags with fused RoPE: lane holds Q[q = q0w+q32][kd*16 + hi*8 + e], rope pairs
  // (2i, 2i+1) are adjacent elements; i = kd*8 + hi*4 + j for pair j in frag kd.
  short8 qv[4];
  {
    const int s = q0w + q32;
    const unsigned short* Qp = qkv + (size_t)(b * 2048 + s) * 3072 + h * 64 + hi * 8;
    const float* cp = cosb + s * 32 + hi * 4;
    const float* sp = sinb + s * 32 + hi * 4;
    const float SC = 0.18033688011112042f;   // (1/8) * log2(e): exp2-domain softmax scale
    #pragma unroll
    for (int kd = 0; kd < 4; kd++){
      short8 raw = *reinterpret_cast<const short8*>(Qp + kd * 16);
      float4 c4 = *reinterpret_cast<const float4*>(cp + kd * 8);
      float4 s4 = *reinterpret_cast<const float4*>(sp + kd * 8);
      unsigned pk[4];
      #pragma unroll
      for (int j = 0; j < 4; j++){
        float t0 = bfu2f((unsigned short)raw[2 * j]);
        float t1 = bfu2f((unsigned short)raw[2 * j + 1]);
        float cc = (&c4.x)[j], sn = (&s4.x)[j];
        pk[j] = cvt_pk_bf16((t0 * cc - t1 * sn) * SC, (t0 * sn + t1 * cc) * SC);
      }
      i32x4 q_ = {(int)pk[0], (int)pk[1], (int)pk[2], (int)pk[3]};
      qv[kd] = __builtin_bit_cast(short8, q_);
    }
  }

  const short8 ones = {0x3F80, 0x3F80, 0x3F80, 0x3F80, 0x3F80, 0x3F80, 0x3F80, 0x3F80};

  f32x16 accA = {}, accB = {};   // O cols d = dh*32 + q32; rows q via reg map
  f32x16 accl = {};              // denominator (all cols identical)

  // build one PV A-frag (k-halfslice of 16) from 8 z-regs starting at R0
#define MKAP(Z, R0, AP) { \
    unsigned A_ = cvt_pk_bf16(Z[R0+0], Z[R0+1]); \
    unsigned B_ = cvt_pk_bf16(Z[R0+2], Z[R0+3]); \
    unsigned C_ = cvt_pk_bf16(Z[R0+4], Z[R0+5]); \
    unsigned D_ = cvt_pk_bf16(Z[R0+6], Z[R0+7]); \
    i32x2 s1_ = pl32swap((int)A_, (int)C_); \
    i32x2 s2_ = pl32swap((int)B_, (int)D_); \
    i32x4 q_ = {s1_[0], s2_[0], s1_[1], s2_[1]}; \
    AP = __builtin_bit_cast(short8, q_); \
  }

  stage(0, 0);
  vm_wait<0>();
  __builtin_amdgcn_s_barrier();

  for (int t = 0; t < nt; ++t){
    const int kv0 = t * 64;
    const int buf = t & 1;
    if (t + 1 < nt) stage((t + 1) * 64, buf ^ 1);   // prefetch stays in flight over compute

    // fully-masked tile for this wave: skip compute, keep sync protocol
    if (kv0 <= q0w + 31){
      const unsigned short* sKc = &sK[buf][0];
      const unsigned short* sVc = &sV[buf][0];

      // ---- S^T = K Q^T (two 32x32 tiles: k 0-31, 32-63) ----
      f32x16 z0 = {}, z1 = {};
      __builtin_amdgcn_s_setprio(1);
      #pragma unroll
      for (int kd = 0; kd < 4; kd++){
        const int u = kd * 2 + hi;
        short8 ak0 = *reinterpret_cast<const short8*>(&sKc[swz64(q32, u)]);
        short8 ak1 = *reinterpret_cast<const short8*>(&sKc[swz64(32 + q32, u)]);
        z0 = __builtin_amdgcn_mfma_f32_32x32x16_bf16(ak0, qv[kd], z0, 0, 0, 0);
        z1 = __builtin_amdgcn_mfma_f32_32x32x16_bf16(ak1, qv[kd], z1, 0, 0, 0);
      }
      __builtin_amdgcn_s_setprio(0);

      // ---- causal mask (wave-uniform branch; near-diagonal tiles) ----
      if (kv0 + 63 > q0w){
        const int qg = q0w + q32;
        #pragma unroll
        for (int r = 0; r < 16; r++){
          const int kr = (r & 3) + 8 * (r >> 2) + 4 * hi;
          if (kv0 + kr > qg)      z0[r] = -1e30f;
          if (kv0 + 32 + kr > qg) z1[r] = -1e30f;
        }
      }

      // ---- P = exp2(S) directly (no max subtraction; lane-local row; masked -> 0) ----
      #pragma unroll
      for (int r = 0; r < 16; r++){
        z0[r] = __builtin_amdgcn_exp2f(z0[r]);
        z1[r] = __builtin_amdgcn_exp2f(z1[r]);
      }

      // ---- PV + ones-denominator, per k-tile (in-register P via cvt_pk + permlane) ----
      short8 apA, apB;
      __builtin_amdgcn_s_setprio(1);
      // kt = 0: k-slices 0,1
      MKAP(z0, 0, apA)
      MKAP(z0, 8, apB)
      accl = __builtin_amdgcn_mfma_f32_32x32x16_bf16(apA, ones, accl, 0, 0, 0);
      accl = __builtin_amdgcn_mfma_f32_32x32x16_bf16(apB, ones, accl, 0, 0, 0);
      {
        short8 bv;
        bv = *reinterpret_cast<const short8*>(&sVc[swz64(q32, 0 * 2 + hi)]);
        accA = __builtin_amdgcn_mfma_f32_32x32x16_bf16(apA, bv, accA, 0, 0, 0);
        bv = *reinterpret_cast<const short8*>(&sVc[swz64(q32, 1 * 2 + hi)]);
        accA = __builtin_amdgcn_mfma_f32_32x32x16_bf16(apB, bv, accA, 0, 0, 0);
        bv = *reinterpret_cast<const short8*>(&sVc[swz64(32 + q32, 0 * 2 + hi)]);
        accB = __builtin_amdgcn_mfma_f32_32x32x16_bf16(apA, bv, accB, 0, 0, 0);
        bv = *reinterpret_cast<const short8*>(&sVc[swz64(32 + q32, 1 * 2 + hi)]);
        accB = __builtin_amdgcn_mfma_f32_32x32x16_bf16(apB, bv, accB, 0, 0, 0);
      }
      // kt = 1: k-slices 2,3
      MKAP(z1, 0, apA)
      MKAP(z1, 8, apB)
      accl = __builtin_amdgcn_mfma_f32_32x32x16_bf16(apA, ones, accl, 0, 0, 0);
      accl = __builtin_amdgcn_mfma_f32_32x32x16_bf16(apB, ones, accl, 0, 0, 0);
      {
        short8 bv;
        bv = *reinterpret_cast<const short8*>(&sVc[swz64(q32, 2 * 2 + hi)]);
        accA = __builtin_amdgcn_mfma_f32_32x32x16_bf16(apA, bv, accA, 0, 0, 0);
        bv = *reinterpret_cast<const short8*>(&sVc[swz64(q32, 3 * 2 + hi)]);
        accA = __builtin_amdgcn_mfma_f32_32x32x16_bf16(apB, bv, accA, 0, 0, 0);
        bv = *reinterpret_cast<const short8*>(&sVc[swz64(32 + q32, 2 * 2 + hi)]);
        accB = __builtin_amdgcn_mfma_f32_32x32x16_bf16(apA, bv, accB, 0, 0, 0);
        bv = *reinterpret_cast<const short8*>(&sVc[swz64(32 + q32, 3 * 2 + hi)]);
        accB = __builtin_amdgcn_mfma_f32_32x32x16_bf16(apB, bv, accB, 0, 0, 0);
      }
      __builtin_amdgcn_s_setprio(0);
    }

    vm_wait<0>();
    __builtin_amdgcn_s_barrier();
  }
#undef MKAP

  // ---- epilogue: normalize rows (accl rows align with acc rows) and store ----
  #pragma unroll
  for (int r = 0; r < 16; r++){
    const float inv = 1.0f / accl[r];
    const int qrow = q0w + (r & 3) + 8 * (r >> 2) + 4 * hi;
    const size_t base = (size_t)(b * 2048 + qrow) * 2048 + h * 64 + q32;
    O[base]      = f2bfu(accA[r] * inv);
    O[base + 32] = f2bfu(accB[r] * inv);
  }
}

extern "C" void kernel_launch(void* const* d_in, const int* in_sizes, int n_in,
                              void* d_out, int out_size, void* d_ws, size_t ws_size,
                              hipStream_t stream){
  (void)in_sizes; (void)n_in; (void)out_size; (void)ws_size;
  const float* x  = (const float*)d_in[0];
  const float* cb = (const float*)d_in[1];
  const float* sb = (const float*)d_in[2];
  const float* Wq = (const float*)d_in[3];
  const float* Wk = (const float*)d_in[4];
  const float* Wv = (const float*)d_in[5];
  const float* Wo = (const float*)d_in[6];
  float* out = (float*)d_out;
  char* ws = (char*)d_ws;

  unsigned short* qkv = (unsigned short*)(ws + 0);           // [4096][3072] bf16
  unsigned short* xb  = (unsigned short*)(ws + 25165824);    // [4096][2048] bf16; reused as attn-out
  unsigned short* wt  = (unsigned short*)(ws + 41943040);    // WqkvT [3072][2048]
  unsigned short* wot = (unsigned short*)(ws + 54525952);    // WoT [2048][2048]
  unsigned short* kb  = (unsigned short*)(ws + 71303168);    // roped k [b][kvh][2048][64]
  unsigned short* vt  = (unsigned short*)(ws + 75497472);    // v^T [b][kvh][64][2048]

  prep_in_kernel<<<18432, 256, 0, stream>>>(x, xb, Wq, Wk, Wv, Wo, wt, wot);
  gemm4p_kernel<3, true><<<512, 256, 0, stream>>>(xb, wt, qkv, 4096, 3072, 2048, 16);
  prep_kv_kernel<<<4608, 256, 0, stream>>>(qkv, cb, sb, kb, vt);
  attn_kernel<<<1024, 256, 0, stream>>>(qkv, cb, sb, kb, vt, xb);   // xb now = attn features
  gemm4p_kernel<2, false><<<512, 256, 0, stream>>>(xb, wot, out, 4096, 2048, 2048, 16);
}

// Round 19
// 171.250 us; speedup vs baseline: 1.1442x; 1.0225x over previous
//
#include <hip/hip_runtime.h>
#include <hip/hip_bf16.h>

// Fused attention block: x@Wqkv -> RoPE -> causal GQA flash attention -> @Wo
// bf16 MFMA compute everywhere (2% abs tolerance), f32 I/O.

typedef __attribute__((ext_vector_type(8))) short short8;   // 8 bf16 = 4 VGPR (MFMA A/B frag)
typedef __attribute__((ext_vector_type(4))) float f32x4;    // 16x16 MFMA C/D frag
typedef __attribute__((ext_vector_type(16))) float f32x16;  // 32x32 MFMA C/D frag
typedef __attribute__((ext_vector_type(2))) int i32x2;
typedef __attribute__((ext_vector_type(4))) int i32x4;

__device__ __forceinline__ unsigned short f2bfu(float f){
  unsigned u = __float_as_uint(f);
  u += 0x7FFFu + ((u >> 16) & 1u);      // RNE (no NaNs in this workload)
  return (unsigned short)(u >> 16);
}
__device__ __forceinline__ float bfu2f(unsigned short u){
  return __uint_as_float(((unsigned)u) << 16);
}
// packed f32x2 -> bf16x2 (RNE), single VALU op
__device__ __forceinline__ unsigned cvt_pk_bf16(float lo, float hi){
  unsigned r;
  asm("v_cvt_pk_bf16_f32 %0, %1, %2" : "=v"(r) : "v"(lo), "v"(hi));
  return r;
}
// permlane32_swap: ret[0] = {a_lo, b_lo-of-partner}, ret[1] = {a_hi-of-partner, b_hi}
__device__ __forceinline__ i32x2 pl32swap(int a, int b){
  auto r = __builtin_amdgcn_permlane32_swap(a, b, false, false);
  return __builtin_bit_cast(i32x2, r);
}
// swizzled element offset in a 64-col bf16 row: slot = 16B unit 0..7, XOR row&7
__device__ __forceinline__ int swz64(int row, int slot){
  return row * 64 + (((slot) ^ (row & 7)) << 3);
}
template<int N> __device__ __forceinline__ void vm_wait(){
  if constexpr (N == 10)      asm volatile("s_waitcnt vmcnt(10)" ::: "memory");
  else if constexpr (N == 8)  asm volatile("s_waitcnt vmcnt(8)" ::: "memory");
  else if constexpr (N == 7)  asm volatile("s_waitcnt vmcnt(7)" ::: "memory");
  else if constexpr (N == 6)  asm volatile("s_waitcnt vmcnt(6)" ::: "memory");
  else if constexpr (N == 5)  asm volatile("s_waitcnt vmcnt(5)" ::: "memory");
  else if constexpr (N == 4)  asm volatile("s_waitcnt vmcnt(4)" ::: "memory");
  else if constexpr (N == 3)  asm volatile("s_waitcnt vmcnt(3)" ::: "memory");
  else if constexpr (N == 2)  asm volatile("s_waitcnt vmcnt(2)" ::: "memory");
  else                        asm volatile("s_waitcnt vmcnt(0)" ::: "memory");
}

// ------- merged input prep: x -> bf16 AND all four W transposes, one launch -------
// blocks [0,8192): convx (256 float4 each); [8192,18432): W-transpose 32x32 tiles
// (ids: [0,4096) Wq -> wt, [4096,5120) Wk, [5120,6144) Wv, [6144,10240) Wo -> wot).
__global__ void prep_in_kernel(const float* __restrict__ x, unsigned short* __restrict__ xb,
                               const float* __restrict__ Wq, const float* __restrict__ Wk,
                               const float* __restrict__ Wv, const float* __restrict__ Wo,
                               unsigned short* __restrict__ wt, unsigned short* __restrict__ wot){
  __shared__ float t[32][33];
  const int blk = blockIdx.x;
  const int tid = threadIdx.x;
  if (blk < 8192){
    int i = blk * 256 + tid;
    float4 v = reinterpret_cast<const float4*>(x)[i];
    ushort4 o;
    o.x = f2bfu(v.x); o.y = f2bfu(v.y); o.z = f2bfu(v.z); o.w = f2bfu(v.w);
    reinterpret_cast<ushort4*>(xb)[i] = o;
  } else {
    int tile = blk - 8192;
    const float* in; unsigned short* out; int Nin, bx;
    if (tile < 4096)      { in = Wq; out = wt;                       Nin = 2048; bx = tile & 63;  tile >>= 6; }
    else if (tile < 5120) { in = Wk; out = wt + (size_t)2048 * 2048; Nin = 512;  tile -= 4096; bx = tile & 15; tile >>= 4; }
    else if (tile < 6144) { in = Wv; out = wt + (size_t)2560 * 2048; Nin = 512;  tile -= 5120; bx = tile & 15; tile >>= 4; }
    else                  { in = Wo; out = wot;                      Nin = 2048; tile -= 6144; bx = tile & 63; tile >>= 6; }
    const int c0 = bx * 32, r0 = tile * 32;   // r0 over K=2048, c0 over Nin
    const int tx = tid & 31, ty = tid >> 5;   // 32 x 8
    #pragma unroll
    for (int i = ty; i < 32; i += 8) t[i][tx] = in[(size_t)(r0 + i) * Nin + c0 + tx];
    __syncthreads();
    #pragma unroll
    for (int i = ty; i < 32; i += 8) out[(size_t)(c0 + i) * 2048 + r0 + tx] = f2bfu(t[tx][i]);
  }
}

// ========= 128 x (NF*64) 4-phase bf16 GEMM, 2 blocks/CU: C = A[M][K] * B^T[N][K] =========
// (verified R15/R16/R18) + K-loop rotation by block parity: block parity p starts its
// K-sweep at column koff = p*64 and wraps mod K (accumulation is K-order-independent).
// Co-resident blocks (blockIdx.x, blockIdx.x+256 under round-robin dispatch) get opposite
// parity -> their read-burst/MFMA-burst phases start anti-aligned instead of in-phase
// (discriminator for the phase-locking theory: both blocks bursting ds_read together would
// serialize on the one LDS pipe and idle together during MFMA, capping MfmaUtil at ~35%).
#define PH4(SLOT,KK,VMW,...) { \
  const unsigned short* sAc = &sA[SLOT][(KK)*4096]; \
  const unsigned short* sBc = &sB[SLOT][(KK)*RB]; \
  short8 afr[4]; short8 bfr[6]; \
  _Pragma("unroll") for (int m_ = 0; m_ < 4; m_++) \
    afr[m_] = *reinterpret_cast<const short8*>(sAc + aOff[m_]); \
  _Pragma("unroll") for (int n_ = 0; n_ < NFR; n_++) \
    bfr[n_] = *reinterpret_cast<const short8*>(sBc + bOff[n_]); \
  __VA_ARGS__; \
  __builtin_amdgcn_s_barrier(); \
  asm volatile("s_waitcnt lgkmcnt(0)" ::: "memory"); \
  __builtin_amdgcn_sched_barrier(0); \
  __builtin_amdgcn_s_setprio(1); \
  _Pragma("unroll") for (int m_ = 0; m_ < 4; m_++){ \
    _Pragma("unroll") for (int n_ = 0; n_ < NFR; n_++){ \
      acc[m_][n_] = __builtin_amdgcn_mfma_f32_16x16x32_bf16(afr[m_], bfr[n_], acc[m_][n_], 0, 0, 0); }} \
  __builtin_amdgcn_s_setprio(0); \
  VMW; \
  __builtin_amdgcn_s_barrier(); \
}

template<int NF, bool OUTBF16>
__global__ __launch_bounds__(256, 2) void gemm4p_kernel(const unsigned short* __restrict__ A,
                                                        const unsigned short* __restrict__ B,
                                                        void* __restrict__ Cp,
                                                        int M, int N, int K, int nbx){
  constexpr int NFR = 2 * NF;                 // n-frags per wave
  constexpr int RB  = NF * 2048;              // elems per B (slot,kk) region (NF*64 rows x 32)
  constexpr int VMS = 2 * (2 + NF);           // per-phase counted wait (2-phase issue window)
  __shared__ unsigned short sA[2][8192];      // 32 KiB  (slot = 2 kk x 128 rows x 32 elems)
  __shared__ unsigned short sB[2][2 * RB];    // NF=3: 48 KiB, NF=2: 32 KiB
  const int tid = threadIdx.x;
  const int l = tid & 63, w = tid >> 6;       // 4 waves
  const int quad = l >> 4, c16 = l & 15;
  // XCD-aware bijective grid swizzle (gridDim.x % 8 == 0)
  const int cpx = (int)gridDim.x >> 3;
  const int id2 = ((int)blockIdx.x & 7) * cpx + ((int)blockIdx.x >> 3);
  const int bx = id2 % nbx, by = id2 / nbx;
  const int row0 = by * 128, col0 = bx * (NF * 64);
  const int wr = w >> 1, wc = w & 1;
  const int koff = (((int)blockIdx.x >> 8) & 1) * 64;   // K-rotation: anti-phase co-residents
  const int kmask = K - 1;                              // K is a power of two (2048)

  // staging source pointers (pre-swizzled column unit); per-wave: A 2 instr, B NF instr
  const unsigned short* gAp[2];
  const unsigned short* gBp[NF];
  #pragma unroll
  for (int j = 0; j < 2; j++){
    int rl = w * 32 + j * 16 + (l >> 2);
    gAp[j] = A + (size_t)(row0 + rl) * K + ((((l & 3) ^ ((rl >> 1) & 3))) << 3);
  }
  #pragma unroll
  for (int j = 0; j < NF; j++){
    int rl = w * (16 * NF) + j * 16 + (l >> 2);
    gBp[j] = B + (size_t)(col0 + rl) * K + ((((l & 3) ^ ((rl >> 1) & 3))) << 3);
  }

  auto stA = [&](int slot, int kk, int col){
    const int c = (col + koff) & kmask;
    #pragma unroll
    for (int j = 0; j < 2; j++)
      __builtin_amdgcn_global_load_lds((const __attribute__((address_space(1))) void*)(gAp[j] + c),
          (__attribute__((address_space(3))) void*)(&sA[slot][kk * 4096 + w * 1024 + j * 512]), 16, 0, 0);
  };
  auto stB = [&](int slot, int kk, int col){
    const int c = (col + koff) & kmask;
    #pragma unroll
    for (int j = 0; j < NF; j++)
      __builtin_amdgcn_global_load_lds((const __attribute__((address_space(1))) void*)(gBp[j] + c),
          (__attribute__((address_space(3))) void*)(&sB[slot][kk * RB + w * (512 * NF) + j * 512]), 16, 0, 0);
  };

  // reader fragment offsets (within a [row][32] k-half region)
  int aOff[4], bOff[6];
  #pragma unroll
  for (int mf = 0; mf < 4; mf++){
    int row = wr * 64 + mf * 16 + c16;
    aOff[mf] = row * 32 + ((quad ^ ((row >> 1) & 3)) << 3);
  }
  #pragma unroll
  for (int nf = 0; nf < NFR; nf++){
    int row = wc * (NF * 32) + nf * 16 + c16;
    bOff[nf] = row * 32 + ((quad ^ ((row >> 1) & 3)) << 3);
  }

  // prologue: regions (0,0),(0,1),(1,0); vmcnt leaves the last 2 regions in flight
  stA(0, 0, 0);  stB(0, 0, 0);
  stA(0, 1, 32); stB(0, 1, 32);
  stA(1, 0, 64); stB(1, 0, 64);
  vm_wait<VMS>();
  __builtin_amdgcn_s_barrier();

  f32x4 acc[4][6] = {};
  const int NI = K >> 7;   // iterations of 2 K-tiles (BK=64)
  #pragma unroll 1
  for (int j = 0; j < NI - 1; ++j){
    const int t1c  = (2 * j + 1) * 64 + 32;  // tile 2j+1, k1
    const int t2c0 = (2 * j + 2) * 64;       // tile 2j+2, k0
    const int t2c1 = t2c0 + 32;
    const int t3c0 = (2 * j + 3) * 64;       // tile 2j+3, k0
    PH4(0,0, vm_wait<VMS>(), stA(1,1,t1c);  stB(1,1,t1c))
    PH4(0,1, vm_wait<VMS>(), stA(0,0,t2c0); stB(0,0,t2c0))
    PH4(1,0, vm_wait<VMS>(), stA(0,1,t2c1); stB(0,1,t2c1))
    PH4(1,1, vm_wait<VMS>(), stA(1,0,t3c0); stB(1,0,t3c0))
  }
  { // peeled last iteration: only the last rotated tile's k1 remains to stage
    const int t1c = K - 32;
    PH4(0,0, vm_wait<VMS>(), stA(1,1,t1c); stB(1,1,t1c))
    PH4(0,1, vm_wait<0>(), ;)
    PH4(1,0, vm_wait<0>(), ;)
    PH4(1,1, (void)0, ;)
  }

  // epilogue
  #pragma unroll
  for (int mf = 0; mf < 4; mf++)
    #pragma unroll
    for (int nf = 0; nf < NFR; nf++)
      #pragma unroll
      for (int r = 0; r < 4; r++){
        size_t off = (size_t)(row0 + wr * 64 + mf * 16 + quad * 4 + r) * N + (col0 + wc * (NF * 32) + nf * 16 + c16);
        if (OUTBF16) ((unsigned short*)Cp)[off] = f2bfu(acc[mf][nf][r]);
        else         ((float*)Cp)[off] = acc[mf][nf][r];
      }
}

// -------- prep_kv: K-rope (qkv cols [2048,2560) -> kb) + V transpose (cols [2560,3072) -> vt) --------
__global__ void prep_kv_kernel(const unsigned short* __restrict__ qkv, const float* __restrict__ cosb,
                               const float* __restrict__ sinb, unsigned short* __restrict__ Ko,
                               unsigned short* __restrict__ Vt){
  __shared__ float t[64][65];
  const int blk = blockIdx.x;
  const int tid = threadIdx.x;
  if (blk < 4096){
    int j = blk * 256 + tid;
    int m = j >> 8, p = j & 255;
    int kvh = p >> 5, i = p & 31;
    int s = m & 2047, b = m >> 11;
    unsigned pr = *reinterpret_cast<const unsigned*>(qkv + (size_t)m * 3072 + 2048 + kvh * 64 + 2 * i);
    float t0 = bfu2f((unsigned short)(pr & 0xFFFFu));
    float t1 = bfu2f((unsigned short)(pr >> 16));
    float c = cosb[s * 32 + i], sn = sinb[s * 32 + i];
    float o0 = t0 * c - t1 * sn;
    float o1 = t0 * sn + t1 * c;
    unsigned ow = (unsigned)f2bfu(o0) | ((unsigned)f2bfu(o1) << 16);
    *reinterpret_cast<unsigned*>(Ko + ((size_t)(b * 8 + kvh) * 2048 + s) * 64 + 2 * i) = ow;
  } else {
    const int bid2 = blk - 4096;
    const int s0 = (bid2 & 31) * 64, bh = bid2 >> 5;
    const int b = bh >> 3, kvh = bh & 7;
    #pragma unroll
    for (int it = 0; it < 16; it++){
      int id = it * 256 + tid;
      int sl = id >> 6, d = id & 63;
      t[sl][d] = bfu2f(qkv[(size_t)(b * 2048 + s0 + sl) * 3072 + 2560 + kvh * 64 + d]);
    }
    __syncthreads();
    #pragma unroll
    for (int it = 0; it < 16; it++){
      int id = it * 256 + tid;
      int dl = id >> 6, sl = id & 63;
      Vt[((size_t)(b * 8 + kvh) * 64 + dl) * 2048 + s0 + sl] = f2bfu(t[sl][dl]);
    }
  }
}

// ---------------- causal GQA flash attention (32x32 swapped, in-register P, no-max) ----------------
// (verified R13/R16/R17/R18: fused Q-RoPE, launch_bounds(256,4), masked-tile skip)
__global__ __launch_bounds__(256, 4) void attn_kernel(const unsigned short* __restrict__ qkv,
                                                      const float* __restrict__ cosb,
                                                      const float* __restrict__ sinb,
                                                      const unsigned short* __restrict__ Kt,
                                                      const unsigned short* __restrict__ Vt,
                                                      unsigned short* __restrict__ O){
  __shared__ unsigned short sK[2][64 * 64];
  __shared__ unsigned short sV[2][64 * 64];
  const int tid = threadIdx.x;
  const int l = tid & 63, w = tid >> 6;
  const int q32 = l & 31, hi = l >> 5;
  const int bid = blockIdx.x;
  const int qt = 15 - (bid >> 6);         // largest kv-trip blocks dispatch first (LPT)
  const int bh = bid & 63;
  const int b = bh >> 5, h = bh & 31, kvh = h >> 2;
  const int q0w = qt * 128 + w * 32;
  const int nt = 2 * qt + 2;              // uniform across the block's 4 waves

  const unsigned short* Kb = Kt + (size_t)(b * 8 + kvh) * 2048 * 64;
  const unsigned short* Vb = Vt + (size_t)(b * 8 + kvh) * 64 * 2048;

  auto stage = [&](int kv0, int buf){
    #pragma unroll
    for (int c = 0; c < 2; c++){
      const int rl = w * 16 + c * 8 + (l >> 3);
      const int ce = (((l & 7) ^ (l >> 3)) << 3);
      __builtin_amdgcn_global_load_lds(
        (const __attribute__((address_space(1))) void*)(Kb + (size_t)(kv0 + rl) * 64 + ce),
        (__attribute__((address_space(3))) void*)(&sK[buf][(w * 16 + c * 8) * 64]), 16, 0, 0);
      __builtin_amdgcn_global_load_lds(
        (const __attribute__((address_space(1))) void*)(Vb + (size_t)rl * 2048 + kv0 + ce),
        (__attribute__((address_space(3))) void*)(&sV[buf][(w * 16 + c * 8) * 64]), 16, 0, 0);
    }
  };

  // Q B-frags with fused RoPE: lane holds Q[q = q0w+q32][kd*16 + hi*8 + e], rope pairs
  // (2i, 2i+1) are adjacent elements; i = kd*8 + hi*4 + j for pair j in frag kd.
  short8 qv[4];
  {
    const int s = q0w + q32;
    const unsigned short* Qp = qkv + (size_t)(b * 2048 + s) * 3072 + h * 64 + hi * 8;
    const float* cp = cosb + s * 32 + hi * 4;
    const float* sp = sinb + s * 32 + hi * 4;
    const float SC = 0.18033688011112042f;   // (1/8) * log2(e): exp2-domain softmax scale
    #pragma unroll
    for (int kd = 0; kd < 4; kd++){
      short8 raw = *reinterpret_cast<const short8*>(Qp + kd * 16);
      float4 c4 = *reinterpret_cast<const float4*>(cp + kd * 8);
      float4 s4 = *reinterpret_cast<const float4*>(sp + kd * 8);
      unsigned pk[4];
      #pragma unroll
      for (int j = 0; j < 4; j++){
        float t0 = bfu2f((unsigned short)raw[2 * j]);
        float t1 = bfu2f((unsigned short)raw[2 * j + 1]);
        float cc = (&c4.x)[j], sn = (&s4.x)[j];
        pk[j] = cvt_pk_bf16((t0 * cc - t1 * sn) * SC, (t0 * sn + t1 * cc) * SC);
      }
      i32x4 q_ = {(int)pk[0], (int)pk[1], (int)pk[2], (int)pk[3]};
      qv[kd] = __builtin_bit_cast(short8, q_);
    }
  }

  const short8 ones = {0x3F80, 0x3F80, 0x3F80, 0x3F80, 0x3F80, 0x3F80, 0x3F80, 0x3F80};

  f32x16 accA = {}, accB = {};   // O cols d = dh*32 + q32; rows q via reg map
  f32x16 accl = {};              // denominator (all cols identical)

  // build one PV A-frag (k-halfslice of 16) from 8 z-regs starting at R0
#define MKAP(Z, R0, AP) { \
    unsigned A_ = cvt_pk_bf16(Z[R0+0], Z[R0+1]); \
    unsigned B_ = cvt_pk_bf16(Z[R0+2], Z[R0+3]); \
    unsigned C_ = cvt_pk_bf16(Z[R0+4], Z[R0+5]); \
    unsigned D_ = cvt_pk_bf16(Z[R0+6], Z[R0+7]); \
    i32x2 s1_ = pl32swap((int)A_, (int)C_); \
    i32x2 s2_ = pl32swap((int)B_, (int)D_); \
    i32x4 q_ = {s1_[0], s2_[0], s1_[1], s2_[1]}; \
    AP = __builtin_bit_cast(short8, q_); \
  }

  stage(0, 0);
  vm_wait<0>();
  __builtin_amdgcn_s_barrier();

  for (int t = 0; t < nt; ++t){
    const int kv0 = t * 64;
    const int buf = t & 1;
    if (t + 1 < nt) stage((t + 1) * 64, buf ^ 1);   // prefetch stays in flight over compute

    // fully-masked tile for this wave: skip compute, keep sync protocol
    if (kv0 <= q0w + 31){
      const unsigned short* sKc = &sK[buf][0];
      const unsigned short* sVc = &sV[buf][0];

      // ---- S^T = K Q^T (two 32x32 tiles: k 0-31, 32-63) ----
      f32x16 z0 = {}, z1 = {};
      __builtin_amdgcn_s_setprio(1);
      #pragma unroll
      for (int kd = 0; kd < 4; kd++){
        const int u = kd * 2 + hi;
        short8 ak0 = *reinterpret_cast<const short8*>(&sKc[swz64(q32, u)]);
        short8 ak1 = *reinterpret_cast<const short8*>(&sKc[swz64(32 + q32, u)]);
        z0 = __builtin_amdgcn_mfma_f32_32x32x16_bf16(ak0, qv[kd], z0, 0, 0, 0);
        z1 = __builtin_amdgcn_mfma_f32_32x32x16_bf16(ak1, qv[kd], z1, 0, 0, 0);
      }
      __builtin_amdgcn_s_setprio(0);

      // ---- causal mask (wave-uniform branch; near-diagonal tiles) ----
      if (kv0 + 63 > q0w){
        const int qg = q0w + q32;
        #pragma unroll
        for (int r = 0; r < 16; r++){
          const int kr = (r & 3) + 8 * (r >> 2) + 4 * hi;
          if (kv0 + kr > qg)      z0[r] = -1e30f;
          if (kv0 + 32 + kr > qg) z1[r] = -1e30f;
        }
      }

      // ---- P = exp2(S) directly (no max subtraction; lane-local row; masked -> 0) ----
      #pragma unroll
      for (int r = 0; r < 16; r++){
        z0[r] = __builtin_amdgcn_exp2f(z0[r]);
        z1[r] = __builtin_amdgcn_exp2f(z1[r]);
      }

      // ---- PV + ones-denominator, per k-tile (in-register P via cvt_pk + permlane) ----
      short8 apA, apB;
      __builtin_amdgcn_s_setprio(1);
      // kt = 0: k-slices 0,1
      MKAP(z0, 0, apA)
      MKAP(z0, 8, apB)
      accl = __builtin_amdgcn_mfma_f32_32x32x16_bf16(apA, ones, accl, 0, 0, 0);
      accl = __builtin_amdgcn_mfma_f32_32x32x16_bf16(apB, ones, accl, 0, 0, 0);
      {
        short8 bv;
        bv = *reinterpret_cast<const short8*>(&sVc[swz64(q32, 0 * 2 + hi)]);
        accA = __builtin_amdgcn_mfma_f32_32x32x16_bf16(apA, bv, accA, 0, 0, 0);
        bv = *reinterpret_cast<const short8*>(&sVc[swz64(q32, 1 * 2 + hi)]);
        accA = __builtin_amdgcn_mfma_f32_32x32x16_bf16(apB, bv, accA, 0, 0, 0);
        bv = *reinterpret_cast<const short8*>(&sVc[swz64(32 + q32, 0 * 2 + hi)]);
        accB = __builtin_amdgcn_mfma_f32_32x32x16_bf16(apA, bv, accB, 0, 0, 0);
        bv = *reinterpret_cast<const short8*>(&sVc[swz64(32 + q32, 1 * 2 + hi)]);
        accB = __builtin_amdgcn_mfma_f32_32x32x16_bf16(apB, bv, accB, 0, 0, 0);
      }
      // kt = 1: k-slices 2,3
      MKAP(z1, 0, apA)
      MKAP(z1, 8, apB)
      accl = __builtin_amdgcn_mfma_f32_32x32x16_bf16(apA, ones, accl, 0, 0, 0);
      accl = __builtin_amdgcn_mfma_f32_32x32x16_bf16(apB, ones, accl, 0, 0, 0);
      {
        short8 bv;
        bv = *reinterpret_cast<const short8*>(&sVc[swz64(q32, 2 * 2 + hi)]);
        accA = __builtin_amdgcn_mfma_f32_32x32x16_bf16(apA, bv, accA, 0, 0, 0);
        bv = *reinterpret_cast<const short8*>(&sVc[swz64(q32, 3 * 2 + hi)]);
        accA = __builtin_amdgcn_mfma_f32_32x32x16_bf16(apB, bv, accA, 0, 0, 0);
        bv = *reinterpret_cast<const short8*>(&sVc[swz64(32 + q32, 2 * 2 + hi)]);
        accB = __builtin_amdgcn_mfma_f32_32x32x16_bf16(apA, bv, accB, 0, 0, 0);
        bv = *reinterpret_cast<const short8*>(&sVc[swz64(32 + q32, 3 * 2 + hi)]);
        accB = __builtin_amdgcn_mfma_f32_32x32x16_bf16(apB, bv, accB, 0, 0, 0);
      }
      __builtin_amdgcn_s_setprio(0);
    }

    vm_wait<0>();
    __builtin_amdgcn_s_barrier();
  }
#undef MKAP

  // ---- epilogue: normalize rows (accl rows align with acc rows) and store ----
  #pragma unroll
  for (int r = 0; r < 16; r++){
    const float inv = 1.0f / accl[r];
    const int qrow = q0w + (r & 3) + 8 * (r >> 2) + 4 * hi;
    const size_t base = (size_t)(b * 2048 + qrow) * 2048 + h * 64 + q32;
    O[base]      = f2bfu(accA[r] * inv);
    O[base + 32] = f2bfu(accB[r] * inv);
  }
}

extern "C" void kernel_launch(void* const* d_in, const int* in_sizes, int n_in,
                              void* d_out, int out_size, void* d_ws, size_t ws_size,
                              hipStream_t stream){
  (void)in_sizes; (void)n_in; (void)out_size; (void)ws_size;
  const float* x  = (const float*)d_in[0];
  const float* cb = (const float*)d_in[1];
  const float* sb = (const float*)d_in[2];
  const float* Wq = (const float*)d_in[3];
  const float* Wk = (const float*)d_in[4];
  const float* Wv = (const float*)d_in[5];
  const float* Wo = (const float*)d_in[6];
  float* out = (float*)d_out;
  char* ws = (char*)d_ws;

  unsigned short* qkv = (unsigned short*)(ws + 0);           // [4096][3072] bf16
  unsigned short* xb  = (unsigned short*)(ws + 25165824);    // [4096][2048] bf16; reused as attn-out
  unsigned short* wt  = (unsigned short*)(ws + 41943040);    // WqkvT [3072][2048]
  unsigned short* wot = (unsigned short*)(ws + 54525952);    // WoT [2048][2048]
  unsigned short* kb  = (unsigned short*)(ws + 71303168);    // roped k [b][kvh][2048][64]
  unsigned short* vt  = (unsigned short*)(ws + 75497472);    // v^T [b][kvh][64][2048]

  prep_in_kernel<<<18432, 256, 0, stream>>>(x, xb, Wq, Wk, Wv, Wo, wt, wot);
  gemm4p_kernel<3, true><<<512, 256, 0, stream>>>(xb, wt, qkv, 4096, 3072, 2048, 16);
  prep_kv_kernel<<<4608, 256, 0, stream>>>(qkv, cb, sb, kb, vt);
  attn_kernel<<<1024, 256, 0, stream>>>(qkv, cb, sb, kb, vt, xb);   // xb now = attn features
  gemm4p_kernel<2, false><<<512, 256, 0, stream>>>(xb, wot, out, 4096, 2048, 2048, 16);
}